// Round 5
// baseline (6309.652 us; speedup 1.0000x reference)
//
#include <hip/hip_runtime.h>
#include <hip/hip_bf16.h>
#include <math.h>

// ---------------------------------------------------------------------------
// VQGAN forward, fp32, round 5.
//  - conv4s2: 8-wide ow tile, CO_T=8 -> 1024 FMA/ci/thread; kh-outer row
//    loads (xv=18 floats); wave-uniform ballot gate on row masks.
//  - convT: 4-wide j tile, CO_T=4 -> 256 FMA/ci/thread, same gating.
//  - LDS weight staging in linear thread order (no bank conflicts).
//  - FMA order per output unchanged (ci -> kh -> kw) => identical numerics.
// d_out = [recon 16*3*256*256 | q 16*32*32*32 | idx-as-float 16384]
// ---------------------------------------------------------------------------

#define EPS 1e-5f

// ---------------- LDS weight staging (linear layout, coalesced) ------------
// lds4[g4] layout: [u][cic][quad]  (g4 = u*CICHUNK*4 + cic*4 + quad)
template <int Cin, int CO_T, int CICHUNK>
__device__ __forceinline__ void stage_weights(
    const float* __restrict__ wb, int ci0, float4* __restrict__ lds4)
{
    constexpr int W4 = CICHUNK * CO_T * 4;
    for (int g4 = threadIdx.x; g4 < W4; g4 += blockDim.x) {
        int u  = g4 / (CICHUNK * 4);
        int r4 = g4 - u * (CICHUNK * 4);
        lds4[g4] = ((const float4*)(wb + (size_t)u * Cin * 16 + (size_t)ci0 * 16))[r4];
    }
}

// ============== conv k4 s2 p1: 8 ow x CO_T channels per thread =============
template <int Cin, int Cout, int Hin, int Win, int CO_T, int CICHUNK>
__global__ __launch_bounds__(256) void conv8_lds(
    const float* __restrict__ x, const float* __restrict__ w,
    const float* __restrict__ bias, float* __restrict__ y)
{
    constexpr int Hout = Hin / 2, Wout = Win / 2, Wt8 = Wout / 8;
    __shared__ float4 wlds[CICHUNK * CO_T * 4];

    const int n   = blockIdx.z;              // SGPR
    const int co0 = blockIdx.y * CO_T;       // SGPR
    const int local = blockIdx.x * blockDim.x + threadIdx.x;
    const int wt = local & (Wt8 - 1);
    const int oh = local / Wt8;
    const int iw0 = (wt << 4) - 1;           // leftmost input col (may be -1)
    const int ih0 = (oh << 1) - 1;

    const float* __restrict__ xn = x + (size_t)n * Cin * Hin * Win;
    const float* __restrict__ wb = w + (size_t)co0 * Cin * 16;

    const bool cL = (wt > 0);
    const bool cR = (wt < Wt8 - 1);
    const int ieL = cL ? iw0 : 0;            // clamped edge indices (no OOB)
    const int ieR = cR ? iw0 + 17 : 0;

    bool rv[4]; int ro[4];
    #pragma unroll
    for (int k = 0; k < 4; ++k) {
        int r = ih0 + k;
        rv[k] = (r >= 0) && (r < Hin);
        ro[k] = rv[k] ? r : 0;
    }
    const bool rowB = (!rv[0]) || (!rv[3]);
    const bool anyB = (__ballot(rowB) != 0ULL);   // wave-uniform

    float acc[CO_T][8];
    #pragma unroll
    for (int u = 0; u < CO_T; ++u)
        #pragma unroll
        for (int s = 0; s < 8; ++s) acc[u][s] = 0.f;

    for (int ci0 = 0; ci0 < Cin; ci0 += CICHUNK) {
        if (ci0) __syncthreads();
        stage_weights<Cin, CO_T, CICHUNK>(wb, ci0, wlds);
        __syncthreads();

        for (int cic = 0; cic < CICHUNK; ++cic) {
            const float* xp = xn + (size_t)(ci0 + cic) * Hin * Win;
            #pragma unroll
            for (int kh = 0; kh < 4; ++kh) {
                const float* rp = xp + (size_t)ro[kh] * Win;
                float4 m0 = *(const float4*)(rp + (wt << 4));
                float4 m1 = *(const float4*)(rp + (wt << 4) + 4);
                float4 m2 = *(const float4*)(rp + (wt << 4) + 8);
                float4 m3 = *(const float4*)(rp + (wt << 4) + 12);
                float e0 = rp[ieL];
                float e17 = rp[ieR];
                float xv[18];
                xv[0]  = cL ? e0 : 0.f;
                xv[1]  = m0.x; xv[2]  = m0.y; xv[3]  = m0.z; xv[4]  = m0.w;
                xv[5]  = m1.x; xv[6]  = m1.y; xv[7]  = m1.z; xv[8]  = m1.w;
                xv[9]  = m2.x; xv[10] = m2.y; xv[11] = m2.z; xv[12] = m2.w;
                xv[13] = m3.x; xv[14] = m3.y; xv[15] = m3.z; xv[16] = m3.w;
                xv[17] = cR ? e17 : 0.f;
                if (anyB) {                      // only boundary waves pay this
                    bool rk = rv[kh];
                    #pragma unroll
                    for (int c = 0; c < 18; ++c) xv[c] = rk ? xv[c] : 0.f;
                }
                #pragma unroll
                for (int u = 0; u < CO_T; ++u) {
                    float4 wq = wlds[u * (CICHUNK * 4) + cic * 4 + kh];
                    #pragma unroll
                    for (int s = 0; s < 8; ++s) {
                        acc[u][s] = fmaf(xv[2 * s + 0], wq.x, acc[u][s]);
                        acc[u][s] = fmaf(xv[2 * s + 1], wq.y, acc[u][s]);
                        acc[u][s] = fmaf(xv[2 * s + 2], wq.z, acc[u][s]);
                        acc[u][s] = fmaf(xv[2 * s + 3], wq.w, acc[u][s]);
                    }
                }
            }
        }
    }

    #pragma unroll
    for (int u = 0; u < CO_T; ++u) {
        float b = bias[co0 + u];
        float4 o0, o1;
        o0.x = acc[u][0] + b; o0.y = acc[u][1] + b;
        o0.z = acc[u][2] + b; o0.w = acc[u][3] + b;
        o1.x = acc[u][4] + b; o1.y = acc[u][5] + b;
        o1.z = acc[u][6] + b; o1.w = acc[u][7] + b;
        float* yp = y + (((size_t)(n * Cout + co0 + u)) * Hout + oh) * Wout + (wt << 3);
        *(float4*)yp = o0;
        *(float4*)(yp + 4) = o1;
    }
}

// ==================== GroupNorm stats (partial, 2-stage) ===================
__global__ __launch_bounds__(256) void gn_stats(
    const float* __restrict__ y, float2* __restrict__ part,
    int HWshift, int grpC, int K)
{
    const int kblk = blockIdx.x;
    const int bg = blockIdx.y;
    const int b = bg >> 5, g = bg & 31;
    const int C = grpC << 5;
    const size_t base = ((size_t)b * C + (size_t)g * grpC) << HWshift;
    const int count4 = (grpC << HWshift) >> 2;
    const int chunk4 = count4 / K;
    const int ofs4 = kblk * chunk4;
    const float4* y4 = (const float4*)(y + base);

    float s = 0.f, ss = 0.f;
    for (int i = ofs4 + threadIdx.x; i < ofs4 + chunk4; i += 256) {
        float4 v = y4[i];
        s += v.x + v.y + v.z + v.w;
        ss = fmaf(v.x, v.x, ss); ss = fmaf(v.y, v.y, ss);
        ss = fmaf(v.z, v.z, ss); ss = fmaf(v.w, v.w, ss);
    }
    __shared__ float sh0[256];
    __shared__ float sh1[256];
    sh0[threadIdx.x] = s; sh1[threadIdx.x] = ss;
    __syncthreads();
    for (int off = 128; off > 0; off >>= 1) {
        if (threadIdx.x < off) {
            sh0[threadIdx.x] += sh0[threadIdx.x + off];
            sh1[threadIdx.x] += sh1[threadIdx.x + off];
        }
        __syncthreads();
    }
    if (threadIdx.x == 0) {
        float2 p; p.x = sh0[0]; p.y = sh1[0];
        part[bg * K + kblk] = p;
    }
}

// ============== GroupNorm combine + normalize + SiLU (in place) ============
__global__ __launch_bounds__(256) void gn_apply(
    float* __restrict__ y, const float* __restrict__ gamma,
    const float* __restrict__ beta, const float2* __restrict__ part,
    int HWshift, int grpC, int K)
{
    const int kblk = blockIdx.x;
    const int bg = blockIdx.y;
    const int b = bg >> 5, g = bg & 31;
    const int C = grpC << 5;
    const size_t base = ((size_t)b * C + (size_t)g * grpC) << HWshift;
    const int count4 = (grpC << HWshift) >> 2;
    const int chunk4 = count4 / K;
    const int ofs4 = kblk * chunk4;
    float4* y4 = (float4*)(y + base);

    float s = 0.f, ss = 0.f;
    for (int k = 0; k < K; ++k) {
        float2 p = part[bg * K + k];
        s += p.x; ss += p.y;
    }
    const float inv = 1.f / (float)(count4 * 4);
    const float mean = s * inv;
    const float var  = ss * inv - mean * mean;
    const float rstd = rsqrtf(var + EPS);

    const int HW4shift = HWshift - 2;
    for (int i = ofs4 + threadIdx.x; i < ofs4 + chunk4; i += 256) {
        int c = g * grpC + (i >> HW4shift);
        float ga = gamma[c], be = beta[c];
        float4 v = y4[i];
        float t0 = (v.x - mean) * rstd * ga + be;
        float t1 = (v.y - mean) * rstd * ga + be;
        float t2 = (v.z - mean) * rstd * ga + be;
        float t3 = (v.w - mean) * rstd * ga + be;
        v.x = t0 / (1.f + __expf(-t0));
        v.y = t1 / (1.f + __expf(-t1));
        v.z = t2 / (1.f + __expf(-t2));
        v.w = t3 / (1.f + __expf(-t3));
        y4[i] = v;
    }
}

// ====================== 1x1 conv, CO_T channels/thread =====================
template <int Cin, int Cout, int HW, int CO_T>
__global__ __launch_bounds__(256) void conv1x1_k(
    const float* __restrict__ x, const float* __restrict__ w,
    const float* __restrict__ bias, float* __restrict__ y)
{
    const int n   = blockIdx.z;
    const int co0 = blockIdx.y * CO_T;
    const int s = blockIdx.x * 256 + threadIdx.x;
    const float* xp = x + (size_t)n * Cin * HW + s;

    float acc[CO_T];
    #pragma unroll
    for (int u = 0; u < CO_T; ++u) acc[u] = bias[co0 + u];

    for (int ci = 0; ci < Cin; ++ci) {
        float v = xp[(size_t)ci * HW];
        #pragma unroll
        for (int u = 0; u < CO_T; ++u)
            acc[u] = fmaf(v, w[(size_t)(co0 + u) * Cin + ci], acc[u]);
    }
    #pragma unroll
    for (int u = 0; u < CO_T; ++u)
        y[(size_t)(n * Cout + co0 + u) * HW + s] = acc[u];
}

// ============================== VQ lookup ==================================
__global__ __launch_bounds__(256) void cb_norm(
    const float* __restrict__ cb, float* __restrict__ cn)
{
    int j = blockIdx.x * 256 + threadIdx.x;   // 1024 total
    const float* c = cb + (size_t)j * 32;
    float s = 0.f;
    #pragma unroll
    for (int k = 0; k < 32; ++k) s = fmaf(c[k], c[k], s);
    cn[j] = s;
}

__global__ __launch_bounds__(256) void vq_kernel(
    const float* __restrict__ z, const float* __restrict__ cb,
    const float* __restrict__ cn, float* __restrict__ q,
    float* __restrict__ idxf)
{
    const int row = blockIdx.x * 4 + (threadIdx.x >> 6);
    const int lane = threadIdx.x & 63;
    const float* zr = z + (size_t)row * 32;
    float zreg[32];
    #pragma unroll
    for (int k = 0; k < 32; ++k) zreg[k] = zr[k];
    float zn = 0.f;
    #pragma unroll
    for (int k = 0; k < 32; ++k) zn = fmaf(zreg[k], zreg[k], zn);

    float best = 3.4e38f;
    int bj = 0;
    for (int ii = 0; ii < 16; ++ii) {
        int j = lane * 16 + ii;               // lane-ascending code order
        const float* c = cb + (size_t)j * 32;
        float dot = 0.f;
        #pragma unroll
        for (int k = 0; k < 32; ++k) dot = fmaf(zreg[k], c[k], dot);
        float d = zn + cn[j] - 2.f * dot;
        if (d < best) { best = d; bj = j; }
    }
    #pragma unroll
    for (int off = 1; off < 64; off <<= 1) {
        float ob = __shfl_xor(best, off);
        int   oj = __shfl_xor(bj, off);
        if (ob < best || (ob == best && oj < bj)) { best = ob; bj = oj; }
    }
    if (lane < 32) q[(size_t)row * 32 + lane] = cb[(size_t)bj * 32 + lane];
    if (lane == 0) idxf[row] = (float)bj;
}

// ====== conv transpose k4 s2 p1: 4-wide j tile x CO_T channels =============
template <int Cin, int Cout, int Hin, int Win, int CO_T, int CICHUNK, bool TANH>
__global__ __launch_bounds__(256) void convt4p_lds(
    const float* __restrict__ x, const float* __restrict__ w,
    const float* __restrict__ bias, float* __restrict__ y)
{
    constexpr int Wt4 = Win / 4;
    __shared__ float4 wlds[CICHUNK * CO_T * 4];

    const int n   = blockIdx.z;              // SGPR
    const int co0 = blockIdx.y * CO_T;       // SGPR
    const int local = blockIdx.x * blockDim.x + threadIdx.x;
    const int jt = local & (Wt4 - 1);
    const int i  = local / Wt4;
    const int j0 = jt << 2;                  // input cols j0..j0+3 (center)

    const float* __restrict__ xn = x + (size_t)n * Cin * Hin * Win;
    const float* __restrict__ wb = w + (size_t)co0 * Cin * 16;

    const bool rm0 = (i > 0), rm2 = (i + 1 < Hin);
    const int ro0 = rm0 ? (i - 1) : 0;
    const int ro2 = rm2 ? (i + 1) : 0;
    const bool cmL = (jt > 0), cmR = (jt < Wt4 - 1);
    const int ieL = cmL ? j0 - 1 : 0;        // clamped (no OOB)
    const int ieR = cmR ? j0 + 4 : 0;

    const bool rowB = (!rm0) || (!rm2);
    const bool anyB = (__ballot(rowB) != 0ULL);

    float acc[CO_T][4][4];
    #pragma unroll
    for (int u = 0; u < CO_T; ++u)
        #pragma unroll
        for (int p = 0; p < 4; ++p)
            acc[u][p][0] = acc[u][p][1] = acc[u][p][2] = acc[u][p][3] = 0.f;

    for (int ci0 = 0; ci0 < Cin; ci0 += CICHUNK) {
        if (ci0) __syncthreads();
        stage_weights<Cin, CO_T, CICHUNK>(wb, ci0, wlds);
        __syncthreads();

        for (int cic = 0; cic < CICHUNK; ++cic) {
            const float* xp = xn + (size_t)(ci0 + cic) * Hin * Win;
            float xr[3][6];
            {
                const int rows[3] = {ro0, i, ro2};
                #pragma unroll
                for (int r = 0; r < 3; ++r) {
                    const float* rp = xp + (size_t)rows[r] * Win;
                    float4 m = *(const float4*)(rp + j0);
                    float eL = rp[ieL];
                    float eR = rp[ieR];
                    xr[r][0] = cmL ? eL : 0.f;
                    xr[r][1] = m.x; xr[r][2] = m.y; xr[r][3] = m.z; xr[r][4] = m.w;
                    xr[r][5] = cmR ? eR : 0.f;
                }
                if (anyB) {
                    #pragma unroll
                    for (int c = 0; c < 6; ++c) {
                        xr[0][c] = rm0 ? xr[0][c] : 0.f;
                        xr[2][c] = rm2 ? xr[2][c] : 0.f;
                    }
                }
            }
            #pragma unroll
            for (int u = 0; u < CO_T; ++u) {
                const int wbase = u * (CICHUNK * 4) + cic * 4;
                float4 wq0 = wlds[wbase + 0];
                float4 wq1 = wlds[wbase + 1];
                float4 wq2 = wlds[wbase + 2];
                float4 wq3 = wlds[wbase + 3];
                #pragma unroll
                for (int p = 0; p < 4; ++p) {
                    float x00 = xr[0][p], x01 = xr[0][p + 1], x02 = xr[0][p + 2];
                    float x10 = xr[1][p], x11 = xr[1][p + 1], x12 = xr[1][p + 2];
                    float x20 = xr[2][p], x21 = xr[2][p + 1], x22 = xr[2][p + 2];
                    float* a = acc[u][p];
                    a[0] = fmaf(x00, wq0.x, a[0]); a[0] = fmaf(x01, wq0.z, a[0]);
                    a[0] = fmaf(x10, wq2.x, a[0]); a[0] = fmaf(x11, wq2.z, a[0]);
                    a[1] = fmaf(x01, wq0.y, a[1]); a[1] = fmaf(x02, wq0.w, a[1]);
                    a[1] = fmaf(x11, wq2.y, a[1]); a[1] = fmaf(x12, wq2.w, a[1]);
                    a[2] = fmaf(x10, wq1.x, a[2]); a[2] = fmaf(x11, wq1.z, a[2]);
                    a[2] = fmaf(x20, wq3.x, a[2]); a[2] = fmaf(x21, wq3.z, a[2]);
                    a[3] = fmaf(x11, wq1.y, a[3]); a[3] = fmaf(x12, wq1.w, a[3]);
                    a[3] = fmaf(x21, wq3.y, a[3]); a[3] = fmaf(x22, wq3.w, a[3]);
                }
            }
        }
    }

    constexpr int Hout = Hin * 2, Wout = Win * 2;
    #pragma unroll
    for (int u = 0; u < CO_T; ++u) {
        float b = bias[co0 + u];
        float r0[8], r1[8];
        #pragma unroll
        for (int p = 0; p < 4; ++p) {
            r0[2 * p]     = acc[u][p][0] + b;
            r0[2 * p + 1] = acc[u][p][1] + b;
            r1[2 * p]     = acc[u][p][2] + b;
            r1[2 * p + 1] = acc[u][p][3] + b;
        }
        if (TANH) {
            #pragma unroll
            for (int c = 0; c < 8; ++c) { r0[c] = tanhf(r0[c]); r1[c] = tanhf(r1[c]); }
        }
        float* yp = y + (((size_t)(n * Cout + co0 + u)) * Hout + (i << 1)) * Wout + (jt << 3);
        float4 o;
        o.x = r0[0]; o.y = r0[1]; o.z = r0[2]; o.w = r0[3]; *(float4*)yp = o;
        o.x = r0[4]; o.y = r0[5]; o.z = r0[6]; o.w = r0[7]; *(float4*)(yp + 4) = o;
        o.x = r1[0]; o.y = r1[1]; o.z = r1[2]; o.w = r1[3]; *(float4*)(yp + Wout) = o;
        o.x = r1[4]; o.y = r1[5]; o.z = r1[6]; o.w = r1[7]; *(float4*)(yp + Wout + 4) = o;
    }
}

// ================================ launch ===================================
extern "C" void kernel_launch(void* const* d_in, const int* in_sizes, int n_in,
                              void* d_out, int out_size, void* d_ws, size_t ws_size,
                              hipStream_t stream)
{
    const float* x       = (const float*)d_in[0];
    const float* enc0_w  = (const float*)d_in[1];
    const float* enc0_b  = (const float*)d_in[2];
    const float* enc0_g  = (const float*)d_in[3];
    const float* enc0_bt = (const float*)d_in[4];
    const float* enc1_w  = (const float*)d_in[5];
    const float* enc1_b  = (const float*)d_in[6];
    const float* enc1_g  = (const float*)d_in[7];
    const float* enc1_bt = (const float*)d_in[8];
    const float* enc2_w  = (const float*)d_in[9];
    const float* enc2_b  = (const float*)d_in[10];
    const float* enc2_g  = (const float*)d_in[11];
    const float* enc2_bt = (const float*)d_in[12];
    const float* enc3_w  = (const float*)d_in[13];
    const float* enc3_b  = (const float*)d_in[14];
    const float* codebook= (const float*)d_in[15];
    const float* dec0_w  = (const float*)d_in[16];
    const float* dec0_b  = (const float*)d_in[17];
    const float* dec1_w  = (const float*)d_in[18];
    const float* dec1_b  = (const float*)d_in[19];
    const float* dec1_g  = (const float*)d_in[20];
    const float* dec1_bt = (const float*)d_in[21];
    const float* dec2_w  = (const float*)d_in[22];
    const float* dec2_b  = (const float*)d_in[23];
    const float* dec2_g  = (const float*)d_in[24];
    const float* dec2_bt = (const float*)d_in[25];
    const float* dec3_w  = (const float*)d_in[26];
    const float* dec3_b  = (const float*)d_in[27];

    float* ws = (float*)d_ws;
    float*  A  = ws;                       // 33,554,432 floats (134 MB)
    float*  B  = ws + 33554432;            // 16,777,216 floats (67 MB)
    float*  C  = ws + 50331648;            //  8,388,608 floats (33.6 MB)
    float*  Z  = ws + 58720256;            //    524,288 floats (2 MB)
    float*  CN = ws + 59244544;            //      1,024 floats
    float2* GP = (float2*)(ws + 59245568); //      8,192 float2 (gn partials)

    float* out   = (float*)d_out;
    float* recon = out;                    // 3,145,728 floats
    float* qbuf  = out + 3145728;          //   524,288 floats
    float* idxf  = out + 3670016;          //    16,384 floats

    const dim3 blk(256);
    const int K = 16;
    const dim3 gngrid(K, 512);

    // ---------------- encoder ----------------
    // enc0: 16x3x256x256 -> 16x128x128x128  (items 128*16=2048 -> gx=8)
    conv8_lds<3, 128, 256, 256, 8, 3><<<dim3(8, 16, 16), blk, 0, stream>>>(
        x, enc0_w, enc0_b, A);
    gn_stats<<<gngrid, blk, 0, stream>>>(A, GP, 14, 4, K);
    gn_apply<<<gngrid, blk, 0, stream>>>(A, enc0_g, enc0_bt, GP, 14, 4, K);

    // enc1: -> 16x256x64x64  (items 64*8=512 -> gx=2)
    conv8_lds<128, 256, 128, 128, 8, 64><<<dim3(2, 32, 16), blk, 0, stream>>>(
        A, enc1_w, enc1_b, B);
    gn_stats<<<gngrid, blk, 0, stream>>>(B, GP, 12, 8, K);
    gn_apply<<<gngrid, blk, 0, stream>>>(B, enc1_g, enc1_bt, GP, 12, 8, K);

    // enc2: -> 16x512x32x32  (items 32*4=128 -> gx=1, block=128)
    conv8_lds<256, 512, 64, 64, 8, 64><<<dim3(1, 64, 16), dim3(128), 0, stream>>>(
        B, enc2_w, enc2_b, C);
    gn_stats<<<gngrid, blk, 0, stream>>>(C, GP, 10, 16, K);
    gn_apply<<<gngrid, blk, 0, stream>>>(C, enc2_g, enc2_bt, GP, 10, 16, K);

    // enc3 1x1: -> z 16x32x32x32
    conv1x1_k<512, 32, 1024, 8><<<dim3(4, 4, 16), blk, 0, stream>>>(
        C, enc3_w, enc3_b, Z);

    // ---------------- VQ ----------------
    cb_norm<<<dim3(4), blk, 0, stream>>>(codebook, CN);
    vq_kernel<<<dim3(16384 / 4), blk, 0, stream>>>(Z, codebook, CN, qbuf, idxf);

    // ---------------- decoder ----------------
    // dec0 1x1: q -> 16x512x32x32 (into A)
    conv1x1_k<32, 512, 1024, 8><<<dim3(4, 64, 16), blk, 0, stream>>>(
        qbuf, dec0_w, dec0_b, A);

    // dec1 convT: -> 16x256x64x64 (into B)  (items 32*8=256 -> gx=1)
    convt4p_lds<512, 256, 32, 32, 4, 64, false><<<dim3(1, 64, 16), blk, 0, stream>>>(
        A, dec1_w, dec1_b, B);
    gn_stats<<<gngrid, blk, 0, stream>>>(B, GP, 12, 8, K);
    gn_apply<<<gngrid, blk, 0, stream>>>(B, dec1_g, dec1_bt, GP, 12, 8, K);

    // dec2 convT: -> 16x128x128x128 (into A)  (items 64*16=1024 -> gx=4)
    convt4p_lds<256, 128, 64, 64, 4, 64, false><<<dim3(4, 32, 16), blk, 0, stream>>>(
        B, dec2_w, dec2_b, A);
    gn_stats<<<gngrid, blk, 0, stream>>>(A, GP, 14, 4, K);
    gn_apply<<<gngrid, blk, 0, stream>>>(A, dec2_g, dec2_bt, GP, 14, 4, K);

    // dec3 convT + tanh: -> recon 16x3x256x256  (items 128*32=4096 -> gx=16)
    convt4p_lds<128, 3, 128, 128, 3, 128, true><<<dim3(16, 1, 16), blk, 0, stream>>>(
        A, dec3_w, dec3_b, recon);
}

// Round 7
// 4110.608 us; speedup vs baseline: 1.5350x; 1.5350x over previous
//
#include <hip/hip_runtime.h>
#include <hip/hip_bf16.h>
#include <math.h>

// ---------------------------------------------------------------------------
// VQGAN forward, round 7: fp32 encoder (proven, idx-exact) + MFMA bf16
// decoder (dec1/dec2, NS=1).
//  - idx is the binding correctness constraint (scalar threshold broadcast);
//    encoder numerics identical to rounds 1-5 passing runs.
//  - Decoder MFMA doubles as a layout-correctness experiment: absmax ~0.01
//    => fragment maps right (port encoder next); absmax O(1) => map wrong.
// d_out = [recon 16*3*256*256 | q 16*32*32*32 | idx-as-float 16384]
// ---------------------------------------------------------------------------

#define EPS 1e-5f
typedef unsigned short ushort_t;
typedef __attribute__((ext_vector_type(8))) short bf16x8;
typedef __attribute__((ext_vector_type(4))) float f32x4;
typedef __attribute__((ext_vector_type(4))) unsigned int u32x4;

__device__ __forceinline__ ushort_t f2bf(float x) {
    __hip_bfloat16 h = __float2bfloat16(x);
    return __builtin_bit_cast(ushort_t, h);
}
__device__ __forceinline__ float bf2f(ushort_t u) {
    __hip_bfloat16 h = __builtin_bit_cast(__hip_bfloat16, u);
    return __bfloat162float(h);
}
template <int NS>
__device__ __forceinline__ void splitNS(float x, ushort_t* p) {
    float r = x;
    #pragma unroll
    for (int s = 0; s < NS; ++s) {
        ushort_t u = f2bf(r);
        p[s] = u;
        if (s + 1 < NS) r -= bf2f(u);
    }
}

// ============== decoder weight pre-split (convT reindex) ===================
// out[((s*4+p)*Cout + co)*Cin*4 + ci*4 + a*2 + b] = split_s(w[co][ci][2a+di][2b+dj])
template <int Cout, int Cin, int NS>
__global__ __launch_bounds__(256) void wsplit_convt(
    const float* __restrict__ w, ushort_t* __restrict__ o)
{
    int idx = blockIdx.x * 256 + threadIdx.x;
    if (idx >= 4 * Cout * Cin * 4) return;
    int b  = idx & 1;
    int a  = (idx >> 1) & 1;
    int ci = (idx >> 2) % Cin;
    int co = ((idx >> 2) / Cin) % Cout;
    int p  = ((idx >> 2) / Cin) / Cout;
    int di = p >> 1, dj = p & 1;
    float v = w[(((size_t)co * Cin + ci) * 4 + (2 * a + di)) * 4 + (2 * b + dj)];
    ushort_t sp[NS];
    splitNS<NS>(v, sp);
    #pragma unroll
    for (int s = 0; s < NS; ++s)
        o[(((size_t)(s * 4 + p) * Cout + co) * Cin + ci) * 4 + a * 2 + b] = sp[s];
}

// ================= MFMA convT k4 s2 p1 (per-parity GEMM) ===================
// parity p=(di,dj): y[2i+di][2j+dj] = sum_ci sum_{a,b} x[i-1+di+a][j-1+dj+b]
//                                     * w[co][ci][2a+di][2b+dj]
// k = ci*4 + a*2 + b. LDS: 2 rows x 2 pair-alignment copies:
// E[d]=(2d,2d+1), O[d]=(2d-1,2d); pair at col c -> copy c&1, index (c+1)>>1.
template <int Cin, int Cout, int Hin, int Win, int CO_WAVES, int M_WAVES, int KC, int NS>
__global__ __launch_bounds__(256) void mfconvt(
    const float* __restrict__ x, const ushort_t* __restrict__ wsp,
    const float* __restrict__ bias, float* __restrict__ y)
{
    constexpr int NDp = Win / 2 + 2;
    constexpr int CO_B = CO_WAVES * 32;
    static_assert(CO_WAVES * M_WAVES == 4, "4 waves");
    static_assert(M_WAVES * 32 == Win, "block spans full row");
    static_assert(KC % 8 == 0, "k-step = 8 ci");
    __shared__ unsigned int Xs[NS * KC * 2 * 2 * NDp];

    const int bi = blockIdx.x;
    const int i = bi >> 2;
    const int p = bi & 3;
    const int di = p >> 1, dj = p & 1;
    const int n = blockIdx.z;
    const int co_base = blockIdx.y * CO_B;
    const int tid = threadIdx.x;
    const int wv = tid >> 6, lane = tid & 63;
    const int cw = wv / M_WAVES, mw = wv % M_WAVES;
    const int co_w0 = co_base + cw * 32;
    const int m_w0 = mw * 32;
    const int q = lane >> 4, l15 = lane & 15;

    const int r0 = i - 1 + di, r1 = i + di;
    const bool v0 = (r0 >= 0), v1 = (r1 < Hin);
    const int r0c = v0 ? r0 : 0, r1c = v1 ? r1 : 0;

    f32x4 acc[2][2];
    #pragma unroll
    for (int a = 0; a < 2; ++a)
        #pragma unroll
        for (int b = 0; b < 2; ++b) acc[a][b] = (f32x4){0.f, 0.f, 0.f, 0.f};

    constexpr int SEGW = Win / 4;
    constexpr int SEGS = KC * 2 * SEGW;

    for (int ci0 = 0; ci0 < Cin; ci0 += KC) {
        if (ci0) __syncthreads();
        for (int seg = tid; seg < SEGS; seg += 256) {
            const int c0 = (seg % SEGW) * 4;
            const int rem = seg / SEGW;
            const int a = rem & 1;
            const int ci = rem >> 1;
            const bool rok = a ? v1 : v0;
            const int gr = a ? r1c : r0c;
            const float* rp = x + ((size_t)(n * Cin + ci0 + ci) * Hin + gr) * Win;
            float v[5];                               // cols c0-1 .. c0+3
            v[0] = (rok && c0 > 0) ? rp[c0 - 1] : 0.f;
            #pragma unroll
            for (int t = 1; t < 5; ++t) v[t] = rok ? rp[c0 + t - 1] : 0.f;
            ushort_t sp[5][NS];
            #pragma unroll
            for (int t = 0; t < 5; ++t) splitNS<NS>(v[t], sp[t]);
            #pragma unroll
            for (int s = 0; s < NS; ++s) {
                const int base = ((s * KC + ci) * 2 + a) * 2 * NDp;
                Xs[base + (c0 >> 1)]           = (unsigned)sp[1][s] | ((unsigned)sp[2][s] << 16);
                Xs[base + (c0 >> 1) + 1]       = (unsigned)sp[3][s] | ((unsigned)sp[4][s] << 16);
                Xs[base + NDp + (c0 >> 1)]     = (unsigned)sp[0][s] | ((unsigned)sp[1][s] << 16);
                Xs[base + NDp + (c0 >> 1) + 1] = (unsigned)sp[2][s] | ((unsigned)sp[3][s] << 16);
                if (c0 == Win - 4)
                    Xs[base + NDp + (Win >> 1)] = (unsigned)sp[4][s];
            }
        }
        __syncthreads();

        #pragma unroll
        for (int cs = 0; cs < KC; cs += 8) {
            bf16x8 af[2][NS];
            #pragma unroll
            for (int cf = 0; cf < 2; ++cf) {
                const int co = co_w0 + cf * 16 + l15;
                #pragma unroll
                for (int s = 0; s < NS; ++s) {
                    const ushort_t* ap = wsp +
                        ((size_t)(s * 4 + p) * Cout + co) * ((size_t)Cin * 4) +
                        (size_t)(ci0 + cs) * 4 + q * 8;
                    af[cf][s] = *(const bf16x8*)ap;
                }
            }
            bf16x8 bfr[2][NS];
            const int ciA = cs + q * 2;
            #pragma unroll
            for (int mf = 0; mf < 2; ++mf) {
                const int m = m_w0 + mf * 16 + l15;
                const int c = m - 1 + dj;
                const int copy = c & 1;
                const int idx = (c + 1) >> 1;
                #pragma unroll
                for (int s = 0; s < NS; ++s) {
                    u32x4 bd;
                    bd.x = Xs[((s * KC + ciA) * 2 + 0) * 2 * NDp + copy * NDp + idx];
                    bd.y = Xs[((s * KC + ciA) * 2 + 1) * 2 * NDp + copy * NDp + idx];
                    bd.z = Xs[((s * KC + ciA + 1) * 2 + 0) * 2 * NDp + copy * NDp + idx];
                    bd.w = Xs[((s * KC + ciA + 1) * 2 + 1) * 2 * NDp + copy * NDp + idx];
                    bfr[mf][s] = __builtin_bit_cast(bf16x8, bd);
                }
            }
            #pragma unroll
            for (int sa = 0; sa < NS; ++sa)
                #pragma unroll
                for (int sb = 0; sb < NS; ++sb) {
                    if (sa + sb >= NS) continue;
                    #pragma unroll
                    for (int cf = 0; cf < 2; ++cf)
                        #pragma unroll
                        for (int mf = 0; mf < 2; ++mf)
                            acc[cf][mf] = __builtin_amdgcn_mfma_f32_16x16x32_bf16(
                                af[cf][sa], bfr[mf][sb], acc[cf][mf], 0, 0, 0);
                }
        }
    }

    constexpr int Ho2 = Hin * 2, Wo2 = Win * 2;
    const int orow = 2 * i + di;
    #pragma unroll
    for (int cf = 0; cf < 2; ++cf)
        #pragma unroll
        for (int mf = 0; mf < 2; ++mf) {
            const int ocol = 2 * (m_w0 + mf * 16 + l15) + dj;
            #pragma unroll
            for (int rg = 0; rg < 4; ++rg) {
                const int co = co_w0 + cf * 16 + q * 4 + rg;
                y[(((size_t)n * Cout + co) * Ho2 + orow) * Wo2 + ocol] =
                    acc[cf][mf][rg] + bias[co];
            }
        }
}

// ============== conv k4 s2 p1 (round-3 proven fp32, idx-exact) =============
template <int Cin, int Cout, int Hin, int Win, int CO_T>
__global__ __launch_bounds__(256) void conv4s2_k(
    const float* __restrict__ x, const float* __restrict__ w,
    const float* __restrict__ bias, float* __restrict__ y)
{
    constexpr int Hout = Hin / 2, Wout = Win / 2, Wt = Wout / 4;
    const int n   = blockIdx.z;
    const int co0 = blockIdx.y * CO_T;
    const int local = blockIdx.x * 256 + threadIdx.x;
    const int wt = local & (Wt - 1);
    const int oh = local / Wt;
    const int iw0 = (wt << 3) - 1;
    const int ih0 = (oh << 1) - 1;

    const float* __restrict__ xn = x + (size_t)n * Cin * Hin * Win;
    const float* __restrict__ wb = w + (size_t)co0 * Cin * 16;

    const bool cL = (wt > 0);
    const bool cR = (wt < Wt - 1);

    float acc[CO_T][4];
    #pragma unroll
    for (int u = 0; u < CO_T; ++u)
        acc[u][0] = acc[u][1] = acc[u][2] = acc[u][3] = 0.f;

    bool rv[4]; int ro[4];
    #pragma unroll
    for (int k = 0; k < 4; ++k) {
        int r = ih0 + k;
        rv[k] = (r >= 0) && (r < Hin);
        ro[k] = rv[k] ? r : 0;
    }

    for (int ci = 0; ci < Cin; ++ci) {
        const float* xp = xn + (size_t)ci * Hin * Win;
        float xv[4][10];
        #pragma unroll
        for (int k = 0; k < 4; ++k) {
            const float* rp = xp + (size_t)ro[k] * Win;
            float4 m0 = *(const float4*)(rp + (wt << 3));
            float4 m1 = *(const float4*)(rp + (wt << 3) + 4);
            float e0 = cL ? rp[iw0] : 0.f;
            float e9 = cR ? rp[iw0 + 9] : 0.f;
            bool rk = rv[k];
            xv[k][0] = rk ? e0 : 0.f;
            xv[k][1] = rk ? m0.x : 0.f;
            xv[k][2] = rk ? m0.y : 0.f;
            xv[k][3] = rk ? m0.z : 0.f;
            xv[k][4] = rk ? m0.w : 0.f;
            xv[k][5] = rk ? m1.x : 0.f;
            xv[k][6] = rk ? m1.y : 0.f;
            xv[k][7] = rk ? m1.z : 0.f;
            xv[k][8] = rk ? m1.w : 0.f;
            xv[k][9] = rk ? e9 : 0.f;
        }
        #pragma unroll
        for (int u = 0; u < CO_T; ++u) {
            const float* wp = wb + ((size_t)u * Cin + ci) * 16;  // uniform
            #pragma unroll
            for (int kh = 0; kh < 4; ++kh) {
                #pragma unroll
                for (int kw = 0; kw < 4; ++kw) {
                    float wv = wp[kh * 4 + kw];
                    acc[u][0] = fmaf(xv[kh][kw + 0], wv, acc[u][0]);
                    acc[u][1] = fmaf(xv[kh][kw + 2], wv, acc[u][1]);
                    acc[u][2] = fmaf(xv[kh][kw + 4], wv, acc[u][2]);
                    acc[u][3] = fmaf(xv[kh][kw + 6], wv, acc[u][3]);
                }
            }
        }
    }

    #pragma unroll
    for (int u = 0; u < CO_T; ++u) {
        float b = bias[co0 + u];
        float4 o;
        o.x = acc[u][0] + b; o.y = acc[u][1] + b;
        o.z = acc[u][2] + b; o.w = acc[u][3] + b;
        float* yp = y + (((size_t)(n * Cout + co0 + u)) * Hout + oh) * Wout + (wt << 2);
        *(float4*)yp = o;
    }
}

// ==================== GroupNorm 2-stage (proven) ===========================
__global__ __launch_bounds__(256) void gn_stats(
    const float* __restrict__ y, float2* __restrict__ part,
    int HWshift, int grpC, int K)
{
    const int kblk = blockIdx.x;
    const int bg = blockIdx.y;
    const int b = bg >> 5, g = bg & 31;
    const int C = grpC << 5;
    const size_t base = ((size_t)b * C + (size_t)g * grpC) << HWshift;
    const int count4 = (grpC << HWshift) >> 2;
    const int chunk4 = count4 / K;
    const int ofs4 = kblk * chunk4;
    const float4* y4 = (const float4*)(y + base);

    float s = 0.f, ss = 0.f;
    for (int i = ofs4 + threadIdx.x; i < ofs4 + chunk4; i += 256) {
        float4 v = y4[i];
        s += v.x + v.y + v.z + v.w;
        ss = fmaf(v.x, v.x, ss); ss = fmaf(v.y, v.y, ss);
        ss = fmaf(v.z, v.z, ss); ss = fmaf(v.w, v.w, ss);
    }
    __shared__ float sh0[256];
    __shared__ float sh1[256];
    sh0[threadIdx.x] = s; sh1[threadIdx.x] = ss;
    __syncthreads();
    for (int off = 128; off > 0; off >>= 1) {
        if (threadIdx.x < off) {
            sh0[threadIdx.x] += sh0[threadIdx.x + off];
            sh1[threadIdx.x] += sh1[threadIdx.x + off];
        }
        __syncthreads();
    }
    if (threadIdx.x == 0) {
        float2 pp; pp.x = sh0[0]; pp.y = sh1[0];
        part[bg * K + kblk] = pp;
    }
}

__global__ __launch_bounds__(256) void gn_apply(
    float* __restrict__ y, const float* __restrict__ gamma,
    const float* __restrict__ beta, const float2* __restrict__ part,
    int HWshift, int grpC, int K)
{
    const int kblk = blockIdx.x;
    const int bg = blockIdx.y;
    const int b = bg >> 5, g = bg & 31;
    const int C = grpC << 5;
    const size_t base = ((size_t)b * C + (size_t)g * grpC) << HWshift;
    const int count4 = (grpC << HWshift) >> 2;
    const int chunk4 = count4 / K;
    const int ofs4 = kblk * chunk4;
    float4* y4 = (float4*)(y + base);

    float s = 0.f, ss = 0.f;
    for (int k = 0; k < K; ++k) {
        float2 pp = part[bg * K + k];
        s += pp.x; ss += pp.y;
    }
    const float inv = 1.f / (float)(count4 * 4);
    const float mean = s * inv;
    const float var = ss * inv - mean * mean;
    const float rstd = rsqrtf(var + EPS);

    const int HW4shift = HWshift - 2;
    for (int i = ofs4 + threadIdx.x; i < ofs4 + chunk4; i += 256) {
        int c = g * grpC + (i >> HW4shift);
        float ga = gamma[c], be = beta[c];
        float4 v = y4[i];
        float t0 = (v.x - mean) * rstd * ga + be;
        float t1 = (v.y - mean) * rstd * ga + be;
        float t2 = (v.z - mean) * rstd * ga + be;
        float t3 = (v.w - mean) * rstd * ga + be;
        v.x = t0 / (1.f + __expf(-t0));
        v.y = t1 / (1.f + __expf(-t1));
        v.z = t2 / (1.f + __expf(-t2));
        v.w = t3 / (1.f + __expf(-t3));
        y4[i] = v;
    }
}

// ====================== 1x1 conv (proven) ==================================
template <int Cin, int Cout, int HW, int CO_T>
__global__ __launch_bounds__(256) void conv1x1_k(
    const float* __restrict__ x, const float* __restrict__ w,
    const float* __restrict__ bias, float* __restrict__ y)
{
    const int n = blockIdx.z;
    const int co0 = blockIdx.y * CO_T;
    const int s = blockIdx.x * 256 + threadIdx.x;
    const float* xp = x + (size_t)n * Cin * HW + s;

    float acc[CO_T];
    #pragma unroll
    for (int u = 0; u < CO_T; ++u) acc[u] = bias[co0 + u];

    for (int ci = 0; ci < Cin; ++ci) {
        float v = xp[(size_t)ci * HW];
        #pragma unroll
        for (int u = 0; u < CO_T; ++u)
            acc[u] = fmaf(v, w[(size_t)(co0 + u) * Cin + ci], acc[u]);
    }
    #pragma unroll
    for (int u = 0; u < CO_T; ++u)
        y[(size_t)(n * Cout + co0 + u) * HW + s] = acc[u];
}

// ============================== VQ (proven) ================================
__global__ __launch_bounds__(256) void cb_norm(
    const float* __restrict__ cb, float* __restrict__ cn)
{
    int j = blockIdx.x * 256 + threadIdx.x;
    const float* c = cb + (size_t)j * 32;
    float s = 0.f;
    #pragma unroll
    for (int k = 0; k < 32; ++k) s = fmaf(c[k], c[k], s);
    cn[j] = s;
}

__global__ __launch_bounds__(256) void vq_kernel(
    const float* __restrict__ z, const float* __restrict__ cb,
    const float* __restrict__ cn, float* __restrict__ q,
    float* __restrict__ idxf)
{
    const int row = blockIdx.x * 4 + (threadIdx.x >> 6);
    const int lane = threadIdx.x & 63;
    const float* zr = z + (size_t)row * 32;
    float zreg[32];
    #pragma unroll
    for (int k = 0; k < 32; ++k) zreg[k] = zr[k];
    float zn = 0.f;
    #pragma unroll
    for (int k = 0; k < 32; ++k) zn = fmaf(zreg[k], zreg[k], zn);

    float best = 3.4e38f;
    int bj = 0;
    for (int ii = 0; ii < 16; ++ii) {
        int j = lane * 16 + ii;
        const float* c = cb + (size_t)j * 32;
        float dot = 0.f;
        #pragma unroll
        for (int k = 0; k < 32; ++k) dot = fmaf(zreg[k], c[k], dot);
        float d = zn + cn[j] - 2.f * dot;
        if (d < best) { best = d; bj = j; }
    }
    #pragma unroll
    for (int off = 1; off < 64; off <<= 1) {
        float ob = __shfl_xor(best, off);
        int oj = __shfl_xor(bj, off);
        if (ob < best || (ob == best && oj < bj)) { best = ob; bj = oj; }
    }
    if (lane < 32) q[(size_t)row * 32 + lane] = cb[(size_t)bj * 32 + lane];
    if (lane == 0) idxf[row] = (float)bj;
}

// ======= fp32 convT (round-4 proven) — used for dec3 (Cout=3, tanh) ========
template <int Cin, int CO_T, int CICHUNK>
__device__ __forceinline__ void stage_weights(
    const float* __restrict__ wb, int ci0, float4* __restrict__ lds4)
{
    constexpr int W4 = CICHUNK * CO_T * 4;
    for (int g4 = threadIdx.x; g4 < W4; g4 += blockDim.x) {
        int u = g4 / (CICHUNK * 4);
        int r4 = g4 - u * (CICHUNK * 4);
        lds4[g4] = ((const float4*)(wb + (size_t)u * Cin * 16 + (size_t)ci0 * 16))[r4];
    }
}

template <int Cin, int Cout, int Hin, int Win, int CO_T, int CICHUNK, bool TANH>
__global__ __launch_bounds__(256) void convt2_lds(
    const float* __restrict__ x, const float* __restrict__ w,
    const float* __restrict__ bias, float* __restrict__ y)
{
    constexpr int Wt2 = Win / 2;
    __shared__ float4 wlds[CICHUNK * CO_T * 4];

    const int n = blockIdx.z;
    const int co0 = blockIdx.y * CO_T;
    const int local = blockIdx.x * 256 + threadIdx.x;
    const int jt = local & (Wt2 - 1);
    const int i = local / Wt2;
    const int j0 = jt << 1;

    const float* __restrict__ xn = x + (size_t)n * Cin * Hin * Win;
    const float* __restrict__ wb = w + (size_t)co0 * Cin * 16;

    const bool rm0 = (i > 0), rm2 = (i + 1 < Hin);
    const bool cmL = (jt > 0), cmR = (jt < Wt2 - 1);
    const int ro0 = rm0 ? (i - 1) : 0;
    const int ro2 = rm2 ? (i + 1) : 0;

    float acc[CO_T][2][4];
    #pragma unroll
    for (int u = 0; u < CO_T; ++u)
        #pragma unroll
        for (int p = 0; p < 2; ++p)
            acc[u][p][0] = acc[u][p][1] = acc[u][p][2] = acc[u][p][3] = 0.f;

    for (int ci0 = 0; ci0 < Cin; ci0 += CICHUNK) {
        if (ci0) __syncthreads();
        stage_weights<Cin, CO_T, CICHUNK>(wb, ci0, wlds);
        __syncthreads();

        for (int cic = 0; cic < CICHUNK; ++cic) {
            const int ci = ci0 + cic;
            const float* xp = xn + (size_t)ci * Hin * Win;
            float xr[3][4];
            {
                const int rows[3] = {ro0, i, ro2};
                const bool rvn[3] = {rm0, true, rm2};
                #pragma unroll
                for (int r = 0; r < 3; ++r) {
                    const float* rp = xp + (size_t)rows[r] * Win;
                    float2 m = *(const float2*)(rp + j0);
                    float eL = cmL ? rp[j0 - 1] : 0.f;
                    float eR = cmR ? rp[j0 + 2] : 0.f;
                    bool rk = rvn[r];
                    xr[r][0] = rk ? eL : 0.f;
                    xr[r][1] = rk ? m.x : 0.f;
                    xr[r][2] = rk ? m.y : 0.f;
                    xr[r][3] = rk ? eR : 0.f;
                }
            }
            #pragma unroll
            for (int u = 0; u < CO_T; ++u) {
                const int wbase = (cic * CO_T + u) * 4;
                float4 wq0 = wlds[wbase + 0];
                float4 wq1 = wlds[wbase + 1];
                float4 wq2 = wlds[wbase + 2];
                float4 wq3 = wlds[wbase + 3];
                #pragma unroll
                for (int p = 0; p < 2; ++p) {
                    float x00 = xr[0][p], x01 = xr[0][p + 1], x02 = xr[0][p + 2];
                    float x10 = xr[1][p], x11 = xr[1][p + 1], x12 = xr[1][p + 2];
                    float x20 = xr[2][p], x21 = xr[2][p + 1], x22 = xr[2][p + 2];
                    float* a = acc[u][p];
                    a[0] = fmaf(x00, wq0.x, a[0]); a[0] = fmaf(x01, wq0.z, a[0]);
                    a[0] = fmaf(x10, wq2.x, a[0]); a[0] = fmaf(x11, wq2.z, a[0]);
                    a[1] = fmaf(x01, wq0.y, a[1]); a[1] = fmaf(x02, wq0.w, a[1]);
                    a[1] = fmaf(x11, wq2.y, a[1]); a[1] = fmaf(x12, wq2.w, a[1]);
                    a[2] = fmaf(x10, wq1.x, a[2]); a[2] = fmaf(x11, wq1.z, a[2]);
                    a[2] = fmaf(x20, wq3.x, a[2]); a[2] = fmaf(x21, wq3.z, a[2]);
                    a[3] = fmaf(x11, wq1.y, a[3]); a[3] = fmaf(x12, wq1.w, a[3]);
                    a[3] = fmaf(x21, wq3.y, a[3]); a[3] = fmaf(x22, wq3.w, a[3]);
                }
            }
        }
    }

    constexpr int Hout = Hin * 2, Wout = Win * 2;
    #pragma unroll
    for (int u = 0; u < CO_T; ++u) {
        float b = bias[co0 + u];
        float r00 = acc[u][0][0] + b, r01 = acc[u][0][1] + b;
        float r02 = acc[u][1][0] + b, r03 = acc[u][1][1] + b;
        float r10 = acc[u][0][2] + b, r11 = acc[u][0][3] + b;
        float r12 = acc[u][1][2] + b, r13 = acc[u][1][3] + b;
        if (TANH) {
            r00 = tanhf(r00); r01 = tanhf(r01); r02 = tanhf(r02); r03 = tanhf(r03);
            r10 = tanhf(r10); r11 = tanhf(r11); r12 = tanhf(r12); r13 = tanhf(r13);
        }
        float* yp = y + (((size_t)(n * Cout + co0 + u)) * Hout + (i << 1)) * Wout + (jt << 2);
        float4 o;
        o.x = r00; o.y = r01; o.z = r02; o.w = r03; *(float4*)yp = o;
        o.x = r10; o.y = r11; o.z = r12; o.w = r13; *(float4*)(yp + Wout) = o;
    }
}

// ================================ launch ===================================
extern "C" void kernel_launch(void* const* d_in, const int* in_sizes, int n_in,
                              void* d_out, int out_size, void* d_ws, size_t ws_size,
                              hipStream_t stream)
{
    const float* x       = (const float*)d_in[0];
    const float* enc0_w  = (const float*)d_in[1];
    const float* enc0_b  = (const float*)d_in[2];
    const float* enc0_g  = (const float*)d_in[3];
    const float* enc0_bt = (const float*)d_in[4];
    const float* enc1_w  = (const float*)d_in[5];
    const float* enc1_b  = (const float*)d_in[6];
    const float* enc1_g  = (const float*)d_in[7];
    const float* enc1_bt = (const float*)d_in[8];
    const float* enc2_w  = (const float*)d_in[9];
    const float* enc2_b  = (const float*)d_in[10];
    const float* enc2_g  = (const float*)d_in[11];
    const float* enc2_bt = (const float*)d_in[12];
    const float* enc3_w  = (const float*)d_in[13];
    const float* enc3_b  = (const float*)d_in[14];
    const float* codebook= (const float*)d_in[15];
    const float* dec0_w  = (const float*)d_in[16];
    const float* dec0_b  = (const float*)d_in[17];
    const float* dec1_w  = (const float*)d_in[18];
    const float* dec1_b  = (const float*)d_in[19];
    const float* dec1_g  = (const float*)d_in[20];
    const float* dec1_bt = (const float*)d_in[21];
    const float* dec2_w  = (const float*)d_in[22];
    const float* dec2_b  = (const float*)d_in[23];
    const float* dec2_g  = (const float*)d_in[24];
    const float* dec2_bt = (const float*)d_in[25];
    const float* dec3_w  = (const float*)d_in[26];
    const float* dec3_b  = (const float*)d_in[27];

    float* ws = (float*)d_ws;
    float*  A  = ws;                       // 33,554,432 floats (134 MB)
    float*  B  = ws + 33554432;            // 16,777,216 floats (67 MB)
    float*  C  = ws + 50331648;            //  8,388,608 floats (33.6 MB)
    float*  Z  = ws + 58720256;            //    524,288 floats (2 MB)
    float*  CN = ws + 59244544;            //      1,024 floats
    float2* GP = (float2*)(ws + 59245568); //      8,192 float2 (gn partials)

    // decoder split weights (C is dead after enc3 consumed it):
    ushort_t* WD1 = (ushort_t*)C;                 // 4*512*256*4 us = 8 MB
    ushort_t* WD2 = (ushort_t*)(C + 4194304);     // 4*256*128*4 us = 1 MB

    float* out   = (float*)d_out;
    float* recon = out;                    // 3,145,728 floats
    float* qbuf  = out + 3145728;          //   524,288 floats
    float* idxf  = out + 3670016;          //    16,384 floats

    const dim3 blk(256);
    const int K = 16;
    const dim3 gngrid(K, 512);

    // ---------------- encoder (fp32, proven numerics -> idx exact) --------
    conv4s2_k<3, 128, 256, 256, 8><<<dim3(16, 16, 16), blk, 0, stream>>>(
        x, enc0_w, enc0_b, A);
    gn_stats<<<gngrid, blk, 0, stream>>>(A, GP, 14, 4, K);
    gn_apply<<<gngrid, blk, 0, stream>>>(A, enc0_g, enc0_bt, GP, 14, 4, K);

    conv4s2_k<128, 256, 128, 128, 8><<<dim3(4, 32, 16), blk, 0, stream>>>(
        A, enc1_w, enc1_b, B);
    gn_stats<<<gngrid, blk, 0, stream>>>(B, GP, 12, 8, K);
    gn_apply<<<gngrid, blk, 0, stream>>>(B, enc1_g, enc1_bt, GP, 12, 8, K);

    conv4s2_k<256, 512, 64, 64, 8><<<dim3(1, 64, 16), blk, 0, stream>>>(
        B, enc2_w, enc2_b, C);
    gn_stats<<<gngrid, blk, 0, stream>>>(C, GP, 10, 16, K);
    gn_apply<<<gngrid, blk, 0, stream>>>(C, enc2_g, enc2_bt, GP, 10, 16, K);

    conv1x1_k<512, 32, 1024, 8><<<dim3(4, 4, 16), blk, 0, stream>>>(
        C, enc3_w, enc3_b, Z);

    // ---------------- VQ ----------------
    cb_norm<<<dim3(4), blk, 0, stream>>>(codebook, CN);
    vq_kernel<<<dim3(16384 / 4), blk, 0, stream>>>(Z, codebook, CN, qbuf, idxf);

    // ---------------- decoder (MFMA bf16 for dec1/dec2) -------------------
    wsplit_convt<256, 512, 1><<<dim3(8192), blk, 0, stream>>>(dec1_w, WD1);
    wsplit_convt<128, 256, 1><<<dim3(2048), blk, 0, stream>>>(dec2_w, WD2);

    // dec0 1x1: q -> 16x512x32x32 (into A)
    conv1x1_k<32, 512, 1024, 8><<<dim3(4, 64, 16), blk, 0, stream>>>(
        qbuf, dec0_w, dec0_b, A);

    // dec1 convT: -> 16x256x64x64 (into B)  (MFMA bf16)
    mfconvt<512, 256, 32, 32, 4, 1, 16, 1><<<dim3(128, 2, 16), blk, 0, stream>>>(
        A, WD1, dec1_b, B);
    gn_stats<<<gngrid, blk, 0, stream>>>(B, GP, 12, 8, K);
    gn_apply<<<gngrid, blk, 0, stream>>>(B, dec1_g, dec1_bt, GP, 12, 8, K);

    // dec2 convT: -> 16x128x128x128 (into A)  (MFMA bf16)
    mfconvt<256, 128, 64, 64, 2, 2, 16, 1><<<dim3(256, 2, 16), blk, 0, stream>>>(
        B, WD2, dec2_b, A);
    gn_stats<<<gngrid, blk, 0, stream>>>(A, GP, 14, 4, K);
    gn_apply<<<gngrid, blk, 0, stream>>>(A, dec2_g, dec2_bt, GP, 14, 4, K);

    // dec3 convT + tanh: -> recon 16x3x256x256 (fp32)
    convt2_lds<128, 3, 128, 128, 3, 128, true><<<dim3(32, 1, 16), blk, 0, stream>>>(
        A, dec3_w, dec3_b, recon);
}

// Round 8
// 3423.935 us; speedup vs baseline: 1.8428x; 1.2006x over previous
//
#include <hip/hip_runtime.h>
#include <hip/hip_bf16.h>
#include <math.h>

// ---------------------------------------------------------------------------
// VQGAN forward, round 8.
//  - enc1/enc2: NEW clean MFMA tap-GEMM (16 tap-GEMMs, k=ci only, m97-style
//    verified pattern), 3-way bf16 split (6 terms) -> idx-exact precision.
//  - decoder: round-7 kernels unchanged (mfconvt NS=1; bounded outputs).
//  - enc0/dec3/1x1/GN/VQ: proven fp32 kernels.
// d_out = [recon 16*3*256*256 | q 16*32*32*32 | idx-as-float 16384]
// ---------------------------------------------------------------------------

#define EPS 1e-5f
typedef unsigned short ushort_t;
typedef __attribute__((ext_vector_type(8))) short bf16x8;
typedef __attribute__((ext_vector_type(4))) float f32x4;
typedef __attribute__((ext_vector_type(4))) unsigned int u32x4;

__device__ __forceinline__ ushort_t f2bf(float x) {
    __hip_bfloat16 h = __float2bfloat16(x);
    return __builtin_bit_cast(ushort_t, h);
}
__device__ __forceinline__ float bf2f(ushort_t u) {
    __hip_bfloat16 h = __builtin_bit_cast(__hip_bfloat16, u);
    return __bfloat162float(h);
}
template <int NS>
__device__ __forceinline__ void splitNS(float x, ushort_t* p) {
    float r = x;
    #pragma unroll
    for (int s = 0; s < NS; ++s) {
        ushort_t u = f2bf(r);
        p[s] = u;
        if (s + 1 < NS) r -= bf2f(u);
    }
}

// ============ encoder weight pre-split: [s][tap][Cout][Cin] ================
template <int Cout, int Cin>
__global__ __launch_bounds__(256) void wsplit_enc(
    const float* __restrict__ w, ushort_t* __restrict__ o)
{
    int idx = blockIdx.x * 256 + threadIdx.x;
    if (idx >= Cout * Cin * 16) return;
    int tap = idx & 15;
    int ci  = (idx >> 4) % Cin;
    int co  = (idx >> 4) / Cin;
    ushort_t sp[3];
    splitNS<3>(w[idx], sp);
    #pragma unroll
    for (int s = 0; s < 3; ++s)
        o[((size_t)(s * 16 + tap) * Cout + co) * Cin + ci] = sp[s];
}

// ================= MFMA encoder conv k4 s2 p1: tap-GEMMs ===================
// Per block: one oh, 32 m (=ow), 256 co (4 waves x 64co), k = ci (KC=32/chunk).
// B staged in LDS: [s][row(4)][ciq(4)][cpos(68)][cie(8)] ushort, where col c
// (global col = 2*M0-1+c) maps to cpos = (c>>1) + (c&1)*34 (parity interleave
// -> fragment reads are 16B-aligned b128 with 2-way banks). All pad zeros
// resolved at staging (uniform per block).
template <int Cin, int Cout, int Hin, int Win>
__global__ __launch_bounds__(256, 2) void mfenc(
    const float* __restrict__ x, const ushort_t* __restrict__ wsp,
    const float* __restrict__ bias, float* __restrict__ y)
{
    constexpr int Hout = Hin / 2, Wout = Win / 2;
    constexpr int MB = 32;
    constexpr int MT = Wout / MB;
    constexpr int NCOL = 66;
    constexpr int KC = 32;
    __shared__ ushort_t Xs[3 * 4 * 4 * 68 * 8];   // 52 KB

    const int n  = blockIdx.z;
    const int oh = blockIdx.x / MT;       // MT constexpr (1 or 2)
    const int mt = blockIdx.x % MT;
    const int M0 = mt * MB;
    const int co_base = blockIdx.y * 256;
    const int tid = threadIdx.x;
    const int wv = tid >> 6, lane = tid & 63;
    const int q = lane >> 4, l15 = lane & 15;
    const int co_w0 = co_base + wv * 64;

    int ro[4]; bool rv[4];
    #pragma unroll
    for (int k = 0; k < 4; ++k) {
        int r = 2 * oh - 1 + k;
        rv[k] = (r >= 0) && (r < Hin);
        ro[k] = rv[k] ? r : 0;
    }

    f32x4 acc[4][2];
    #pragma unroll
    for (int a = 0; a < 4; ++a)
        #pragma unroll
        for (int b = 0; b < 2; ++b) acc[a][b] = (f32x4){0.f, 0.f, 0.f, 0.f};

    const int sci = tid >> 3;             // 0..31: ci within chunk
    const int sw8 = tid & 7;
    const int sciq = sci >> 3, scie = sci & 7;

    for (int ci0 = 0; ci0 < Cin; ci0 += KC) {
        if (ci0) __syncthreads();
        // ---- stage 4 rows x 66 cols x 32 ci, split-3 ----
        #pragma unroll
        for (int r = 0; r < 4; ++r) {
            const float* rp = x + ((size_t)(n * Cin + ci0 + sci) * Hin + ro[r]) * Win;
            const bool rok = rv[r];
            for (int c = sw8; c < NCOL; c += 8) {
                int gc = 2 * M0 - 1 + c;
                float v = (rok && gc >= 0 && gc < Win) ? rp[gc] : 0.f;
                ushort_t sp[3];
                splitNS<3>(v, sp);
                int cpos = (c >> 1) + (c & 1) * 34;
                #pragma unroll
                for (int s = 0; s < 3; ++s)
                    Xs[((((s * 4 + r) * 4 + sciq) * 68) + cpos) * 8 + scie] = sp[s];
            }
        }
        __syncthreads();

        for (int tap = 0; tap < 16; ++tap) {
            const int kh = tap >> 2, kw = tap & 3;
            bf16x8 af[4][3];
            #pragma unroll
            for (int cf = 0; cf < 4; ++cf) {
                const int co = co_w0 + cf * 16 + l15;
                #pragma unroll
                for (int s = 0; s < 3; ++s)
                    af[cf][s] = *(const bf16x8*)(wsp +
                        ((size_t)(s * 16 + tap) * Cout + co) * Cin + ci0 + q * 8);
            }
            bf16x8 bx[2][3];
            const int cpbase = (kw >> 1) + (kw & 1) * 34;
            #pragma unroll
            for (int mf = 0; mf < 2; ++mf) {
                const int cpos = (mf * 16 + l15) + cpbase;
                #pragma unroll
                for (int s = 0; s < 3; ++s)
                    bx[mf][s] = *(const bf16x8*)(&Xs[((((s * 4 + kh) * 4 + q) * 68) + cpos) * 8]);
            }
            #pragma unroll
            for (int sa = 0; sa < 3; ++sa)
                #pragma unroll
                for (int sb = 0; sb < 3; ++sb) {
                    if (sa + sb >= 3) continue;
                    #pragma unroll
                    for (int cf = 0; cf < 4; ++cf)
                        #pragma unroll
                        for (int mf = 0; mf < 2; ++mf)
                            acc[cf][mf] = __builtin_amdgcn_mfma_f32_16x16x32_bf16(
                                af[cf][sa], bx[mf][sb], acc[cf][mf], 0, 0, 0);
                }
        }
    }

    #pragma unroll
    for (int cf = 0; cf < 4; ++cf)
        #pragma unroll
        for (int mf = 0; mf < 2; ++mf) {
            const int ow = M0 + mf * 16 + l15;
            #pragma unroll
            for (int rg = 0; rg < 4; ++rg) {
                const int co = co_w0 + cf * 16 + q * 4 + rg;
                y[(((size_t)n * Cout + co) * Hout + oh) * Wout + ow] =
                    acc[cf][mf][rg] + bias[co];
            }
        }
}

// ============== decoder weight pre-split (round-7, NS=1) ===================
template <int Cout, int Cin, int NS>
__global__ __launch_bounds__(256) void wsplit_convt(
    const float* __restrict__ w, ushort_t* __restrict__ o)
{
    int idx = blockIdx.x * 256 + threadIdx.x;
    if (idx >= 4 * Cout * Cin * 4) return;
    int b  = idx & 1;
    int a  = (idx >> 1) & 1;
    int ci = (idx >> 2) % Cin;
    int co = ((idx >> 2) / Cin) % Cout;
    int p  = ((idx >> 2) / Cin) / Cout;
    int di = p >> 1, dj = p & 1;
    float v = w[(((size_t)co * Cin + ci) * 4 + (2 * a + di)) * 4 + (2 * b + dj)];
    ushort_t sp[NS];
    splitNS<NS>(v, sp);
    #pragma unroll
    for (int s = 0; s < NS; ++s)
        o[(((size_t)(s * 4 + p) * Cout + co) * Cin + ci) * 4 + a * 2 + b] = sp[s];
}

// ================= MFMA convT (round-7, unchanged) =========================
template <int Cin, int Cout, int Hin, int Win, int CO_WAVES, int M_WAVES, int KC, int NS>
__global__ __launch_bounds__(256) void mfconvt(
    const float* __restrict__ x, const ushort_t* __restrict__ wsp,
    const float* __restrict__ bias, float* __restrict__ y)
{
    constexpr int NDp = Win / 2 + 2;
    constexpr int CO_B = CO_WAVES * 32;
    static_assert(CO_WAVES * M_WAVES == 4, "4 waves");
    static_assert(M_WAVES * 32 == Win, "block spans full row");
    static_assert(KC % 8 == 0, "k-step = 8 ci");
    __shared__ unsigned int Xs[NS * KC * 2 * 2 * NDp];

    const int bi = blockIdx.x;
    const int i = bi >> 2;
    const int p = bi & 3;
    const int di = p >> 1, dj = p & 1;
    const int n = blockIdx.z;
    const int co_base = blockIdx.y * CO_B;
    const int tid = threadIdx.x;
    const int wv = tid >> 6, lane = tid & 63;
    const int cw = wv / M_WAVES, mw = wv % M_WAVES;
    const int co_w0 = co_base + cw * 32;
    const int m_w0 = mw * 32;
    const int q = lane >> 4, l15 = lane & 15;

    const int r0 = i - 1 + di, r1 = i + di;
    const bool v0 = (r0 >= 0), v1 = (r1 < Hin);
    const int r0c = v0 ? r0 : 0, r1c = v1 ? r1 : 0;

    f32x4 acc[2][2];
    #pragma unroll
    for (int a = 0; a < 2; ++a)
        #pragma unroll
        for (int b = 0; b < 2; ++b) acc[a][b] = (f32x4){0.f, 0.f, 0.f, 0.f};

    constexpr int SEGW = Win / 4;
    constexpr int SEGS = KC * 2 * SEGW;

    for (int ci0 = 0; ci0 < Cin; ci0 += KC) {
        if (ci0) __syncthreads();
        for (int seg = tid; seg < SEGS; seg += 256) {
            const int c0 = (seg % SEGW) * 4;
            const int rem = seg / SEGW;
            const int a = rem & 1;
            const int ci = rem >> 1;
            const bool rok = a ? v1 : v0;
            const int gr = a ? r1c : r0c;
            const float* rp = x + ((size_t)(n * Cin + ci0 + ci) * Hin + gr) * Win;
            float v[5];
            v[0] = (rok && c0 > 0) ? rp[c0 - 1] : 0.f;
            #pragma unroll
            for (int t = 1; t < 5; ++t) v[t] = rok ? rp[c0 + t - 1] : 0.f;
            ushort_t sp[5][NS];
            #pragma unroll
            for (int t = 0; t < 5; ++t) splitNS<NS>(v[t], sp[t]);
            #pragma unroll
            for (int s = 0; s < NS; ++s) {
                const int base = ((s * KC + ci) * 2 + a) * 2 * NDp;
                Xs[base + (c0 >> 1)]           = (unsigned)sp[1][s] | ((unsigned)sp[2][s] << 16);
                Xs[base + (c0 >> 1) + 1]       = (unsigned)sp[3][s] | ((unsigned)sp[4][s] << 16);
                Xs[base + NDp + (c0 >> 1)]     = (unsigned)sp[0][s] | ((unsigned)sp[1][s] << 16);
                Xs[base + NDp + (c0 >> 1) + 1] = (unsigned)sp[2][s] | ((unsigned)sp[3][s] << 16);
                if (c0 == Win - 4)
                    Xs[base + NDp + (Win >> 1)] = (unsigned)sp[4][s];
            }
        }
        __syncthreads();

        #pragma unroll
        for (int cs = 0; cs < KC; cs += 8) {
            bf16x8 af[2][NS];
            #pragma unroll
            for (int cf = 0; cf < 2; ++cf) {
                const int co = co_w0 + cf * 16 + l15;
                #pragma unroll
                for (int s = 0; s < NS; ++s) {
                    const ushort_t* ap = wsp +
                        ((size_t)(s * 4 + p) * Cout + co) * ((size_t)Cin * 4) +
                        (size_t)(ci0 + cs) * 4 + q * 8;
                    af[cf][s] = *(const bf16x8*)ap;
                }
            }
            bf16x8 bfr[2][NS];
            const int ciA = cs + q * 2;
            #pragma unroll
            for (int mf = 0; mf < 2; ++mf) {
                const int m = m_w0 + mf * 16 + l15;
                const int c = m - 1 + dj;
                const int copy = c & 1;
                const int idx = (c + 1) >> 1;
                #pragma unroll
                for (int s = 0; s < NS; ++s) {
                    u32x4 bd;
                    bd.x = Xs[((s * KC + ciA) * 2 + 0) * 2 * NDp + copy * NDp + idx];
                    bd.y = Xs[((s * KC + ciA) * 2 + 1) * 2 * NDp + copy * NDp + idx];
                    bd.z = Xs[((s * KC + ciA + 1) * 2 + 0) * 2 * NDp + copy * NDp + idx];
                    bd.w = Xs[((s * KC + ciA + 1) * 2 + 1) * 2 * NDp + copy * NDp + idx];
                    bfr[mf][s] = __builtin_bit_cast(bf16x8, bd);
                }
            }
            #pragma unroll
            for (int sa = 0; sa < NS; ++sa)
                #pragma unroll
                for (int sb = 0; sb < NS; ++sb) {
                    if (sa + sb >= NS) continue;
                    #pragma unroll
                    for (int cf = 0; cf < 2; ++cf)
                        #pragma unroll
                        for (int mf = 0; mf < 2; ++mf)
                            acc[cf][mf] = __builtin_amdgcn_mfma_f32_16x16x32_bf16(
                                af[cf][sa], bfr[mf][sb], acc[cf][mf], 0, 0, 0);
                }
        }
    }

    constexpr int Ho2 = Hin * 2, Wo2 = Win * 2;
    const int orow = 2 * i + di;
    #pragma unroll
    for (int cf = 0; cf < 2; ++cf)
        #pragma unroll
        for (int mf = 0; mf < 2; ++mf) {
            const int ocol = 2 * (m_w0 + mf * 16 + l15) + dj;
            #pragma unroll
            for (int rg = 0; rg < 4; ++rg) {
                const int co = co_w0 + cf * 16 + q * 4 + rg;
                y[(((size_t)n * Cout + co) * Ho2 + orow) * Wo2 + ocol] =
                    acc[cf][mf][rg] + bias[co];
            }
        }
}

// ============== conv k4 s2 p1 (round-3 proven fp32) — enc0 only ============
template <int Cin, int Cout, int Hin, int Win, int CO_T>
__global__ __launch_bounds__(256) void conv4s2_k(
    const float* __restrict__ x, const float* __restrict__ w,
    const float* __restrict__ bias, float* __restrict__ y)
{
    constexpr int Hout = Hin / 2, Wout = Win / 2, Wt = Wout / 4;
    const int n   = blockIdx.z;
    const int co0 = blockIdx.y * CO_T;
    const int local = blockIdx.x * 256 + threadIdx.x;
    const int wt = local & (Wt - 1);
    const int oh = local / Wt;
    const int iw0 = (wt << 3) - 1;
    const int ih0 = (oh << 1) - 1;

    const float* __restrict__ xn = x + (size_t)n * Cin * Hin * Win;
    const float* __restrict__ wb = w + (size_t)co0 * Cin * 16;

    const bool cL = (wt > 0);
    const bool cR = (wt < Wt - 1);

    float acc[CO_T][4];
    #pragma unroll
    for (int u = 0; u < CO_T; ++u)
        acc[u][0] = acc[u][1] = acc[u][2] = acc[u][3] = 0.f;

    bool rv[4]; int ro[4];
    #pragma unroll
    for (int k = 0; k < 4; ++k) {
        int r = ih0 + k;
        rv[k] = (r >= 0) && (r < Hin);
        ro[k] = rv[k] ? r : 0;
    }

    for (int ci = 0; ci < Cin; ++ci) {
        const float* xp = xn + (size_t)ci * Hin * Win;
        float xv[4][10];
        #pragma unroll
        for (int k = 0; k < 4; ++k) {
            const float* rp = xp + (size_t)ro[k] * Win;
            float4 m0 = *(const float4*)(rp + (wt << 3));
            float4 m1 = *(const float4*)(rp + (wt << 3) + 4);
            float e0 = cL ? rp[iw0] : 0.f;
            float e9 = cR ? rp[iw0 + 9] : 0.f;
            bool rk = rv[k];
            xv[k][0] = rk ? e0 : 0.f;
            xv[k][1] = rk ? m0.x : 0.f;
            xv[k][2] = rk ? m0.y : 0.f;
            xv[k][3] = rk ? m0.z : 0.f;
            xv[k][4] = rk ? m0.w : 0.f;
            xv[k][5] = rk ? m1.x : 0.f;
            xv[k][6] = rk ? m1.y : 0.f;
            xv[k][7] = rk ? m1.z : 0.f;
            xv[k][8] = rk ? m1.w : 0.f;
            xv[k][9] = rk ? e9 : 0.f;
        }
        #pragma unroll
        for (int u = 0; u < CO_T; ++u) {
            const float* wp = wb + ((size_t)u * Cin + ci) * 16;
            #pragma unroll
            for (int kh = 0; kh < 4; ++kh) {
                #pragma unroll
                for (int kw = 0; kw < 4; ++kw) {
                    float wv = wp[kh * 4 + kw];
                    acc[u][0] = fmaf(xv[kh][kw + 0], wv, acc[u][0]);
                    acc[u][1] = fmaf(xv[kh][kw + 2], wv, acc[u][1]);
                    acc[u][2] = fmaf(xv[kh][kw + 4], wv, acc[u][2]);
                    acc[u][3] = fmaf(xv[kh][kw + 6], wv, acc[u][3]);
                }
            }
        }
    }

    #pragma unroll
    for (int u = 0; u < CO_T; ++u) {
        float b = bias[co0 + u];
        float4 o;
        o.x = acc[u][0] + b; o.y = acc[u][1] + b;
        o.z = acc[u][2] + b; o.w = acc[u][3] + b;
        float* yp = y + (((size_t)(n * Cout + co0 + u)) * Hout + oh) * Wout + (wt << 2);
        *(float4*)yp = o;
    }
}

// ==================== GroupNorm 2-stage (proven) ===========================
__global__ __launch_bounds__(256) void gn_stats(
    const float* __restrict__ y, float2* __restrict__ part,
    int HWshift, int grpC, int K)
{
    const int kblk = blockIdx.x;
    const int bg = blockIdx.y;
    const int b = bg >> 5, g = bg & 31;
    const int C = grpC << 5;
    const size_t base = ((size_t)b * C + (size_t)g * grpC) << HWshift;
    const int count4 = (grpC << HWshift) >> 2;
    const int chunk4 = count4 / K;
    const int ofs4 = kblk * chunk4;
    const float4* y4 = (const float4*)(y + base);

    float s = 0.f, ss = 0.f;
    for (int i = ofs4 + threadIdx.x; i < ofs4 + chunk4; i += 256) {
        float4 v = y4[i];
        s += v.x + v.y + v.z + v.w;
        ss = fmaf(v.x, v.x, ss); ss = fmaf(v.y, v.y, ss);
        ss = fmaf(v.z, v.z, ss); ss = fmaf(v.w, v.w, ss);
    }
    __shared__ float sh0[256];
    __shared__ float sh1[256];
    sh0[threadIdx.x] = s; sh1[threadIdx.x] = ss;
    __syncthreads();
    for (int off = 128; off > 0; off >>= 1) {
        if (threadIdx.x < off) {
            sh0[threadIdx.x] += sh0[threadIdx.x + off];
            sh1[threadIdx.x] += sh1[threadIdx.x + off];
        }
        __syncthreads();
    }
    if (threadIdx.x == 0) {
        float2 pp; pp.x = sh0[0]; pp.y = sh1[0];
        part[bg * K + kblk] = pp;
    }
}

__global__ __launch_bounds__(256) void gn_apply(
    float* __restrict__ y, const float* __restrict__ gamma,
    const float* __restrict__ beta, const float2* __restrict__ part,
    int HWshift, int grpC, int K)
{
    const int kblk = blockIdx.x;
    const int bg = blockIdx.y;
    const int b = bg >> 5, g = bg & 31;
    const int C = grpC << 5;
    const size_t base = ((size_t)b * C + (size_t)g * grpC) << HWshift;
    const int count4 = (grpC << HWshift) >> 2;
    const int chunk4 = count4 / K;
    const int ofs4 = kblk * chunk4;
    float4* y4 = (float4*)(y + base);

    float s = 0.f, ss = 0.f;
    for (int k = 0; k < K; ++k) {
        float2 pp = part[bg * K + k];
        s += pp.x; ss += pp.y;
    }
    const float inv = 1.f / (float)(count4 * 4);
    const float mean = s * inv;
    const float var = ss * inv - mean * mean;
    const float rstd = rsqrtf(var + EPS);

    const int HW4shift = HWshift - 2;
    for (int i = ofs4 + threadIdx.x; i < ofs4 + chunk4; i += 256) {
        int c = g * grpC + (i >> HW4shift);
        float ga = gamma[c], be = beta[c];
        float4 v = y4[i];
        float t0 = (v.x - mean) * rstd * ga + be;
        float t1 = (v.y - mean) * rstd * ga + be;
        float t2 = (v.z - mean) * rstd * ga + be;
        float t3 = (v.w - mean) * rstd * ga + be;
        v.x = t0 / (1.f + __expf(-t0));
        v.y = t1 / (1.f + __expf(-t1));
        v.z = t2 / (1.f + __expf(-t2));
        v.w = t3 / (1.f + __expf(-t3));
        y4[i] = v;
    }
}

// ====================== 1x1 conv (proven) ==================================
template <int Cin, int Cout, int HW, int CO_T>
__global__ __launch_bounds__(256) void conv1x1_k(
    const float* __restrict__ x, const float* __restrict__ w,
    const float* __restrict__ bias, float* __restrict__ y)
{
    const int n = blockIdx.z;
    const int co0 = blockIdx.y * CO_T;
    const int s = blockIdx.x * 256 + threadIdx.x;
    const float* xp = x + (size_t)n * Cin * HW + s;

    float acc[CO_T];
    #pragma unroll
    for (int u = 0; u < CO_T; ++u) acc[u] = bias[co0 + u];

    for (int ci = 0; ci < Cin; ++ci) {
        float v = xp[(size_t)ci * HW];
        #pragma unroll
        for (int u = 0; u < CO_T; ++u)
            acc[u] = fmaf(v, w[(size_t)(co0 + u) * Cin + ci], acc[u]);
    }
    #pragma unroll
    for (int u = 0; u < CO_T; ++u)
        y[(size_t)(n * Cout + co0 + u) * HW + s] = acc[u];
}

// ============================== VQ (proven) ================================
__global__ __launch_bounds__(256) void cb_norm(
    const float* __restrict__ cb, float* __restrict__ cn)
{
    int j = blockIdx.x * 256 + threadIdx.x;
    const float* c = cb + (size_t)j * 32;
    float s = 0.f;
    #pragma unroll
    for (int k = 0; k < 32; ++k) s = fmaf(c[k], c[k], s);
    cn[j] = s;
}

__global__ __launch_bounds__(256) void vq_kernel(
    const float* __restrict__ z, const float* __restrict__ cb,
    const float* __restrict__ cn, float* __restrict__ q,
    float* __restrict__ idxf)
{
    const int row = blockIdx.x * 4 + (threadIdx.x >> 6);
    const int lane = threadIdx.x & 63;
    const float* zr = z + (size_t)row * 32;
    float zreg[32];
    #pragma unroll
    for (int k = 0; k < 32; ++k) zreg[k] = zr[k];
    float zn = 0.f;
    #pragma unroll
    for (int k = 0; k < 32; ++k) zn = fmaf(zreg[k], zreg[k], zn);

    float best = 3.4e38f;
    int bj = 0;
    for (int ii = 0; ii < 16; ++ii) {
        int j = lane * 16 + ii;
        const float* c = cb + (size_t)j * 32;
        float dot = 0.f;
        #pragma unroll
        for (int k = 0; k < 32; ++k) dot = fmaf(zreg[k], c[k], dot);
        float d = zn + cn[j] - 2.f * dot;
        if (d < best) { best = d; bj = j; }
    }
    #pragma unroll
    for (int off = 1; off < 64; off <<= 1) {
        float ob = __shfl_xor(best, off);
        int oj = __shfl_xor(bj, off);
        if (ob < best || (ob == best && oj < bj)) { best = ob; bj = oj; }
    }
    if (lane < 32) q[(size_t)row * 32 + lane] = cb[(size_t)bj * 32 + lane];
    if (lane == 0) idxf[row] = (float)bj;
}

// ======= fp32 convT (round-4 proven) — dec3 (Cout=3, tanh) =================
template <int Cin, int CO_T, int CICHUNK>
__device__ __forceinline__ void stage_weights(
    const float* __restrict__ wb, int ci0, float4* __restrict__ lds4)
{
    constexpr int W4 = CICHUNK * CO_T * 4;
    for (int g4 = threadIdx.x; g4 < W4; g4 += blockDim.x) {
        int u = g4 / (CICHUNK * 4);
        int r4 = g4 - u * (CICHUNK * 4);
        lds4[g4] = ((const float4*)(wb + (size_t)u * Cin * 16 + (size_t)ci0 * 16))[r4];
    }
}

template <int Cin, int Cout, int Hin, int Win, int CO_T, int CICHUNK, bool TANH>
__global__ __launch_bounds__(256) void convt2_lds(
    const float* __restrict__ x, const float* __restrict__ w,
    const float* __restrict__ bias, float* __restrict__ y)
{
    constexpr int Wt2 = Win / 2;
    __shared__ float4 wlds[CICHUNK * CO_T * 4];

    const int n = blockIdx.z;
    const int co0 = blockIdx.y * CO_T;
    const int local = blockIdx.x * 256 + threadIdx.x;
    const int jt = local & (Wt2 - 1);
    const int i = local / Wt2;
    const int j0 = jt << 1;

    const float* __restrict__ xn = x + (size_t)n * Cin * Hin * Win;
    const float* __restrict__ wb = w + (size_t)co0 * Cin * 16;

    const bool rm0 = (i > 0), rm2 = (i + 1 < Hin);
    const bool cmL = (jt > 0), cmR = (jt < Wt2 - 1);
    const int ro0 = rm0 ? (i - 1) : 0;
    const int ro2 = rm2 ? (i + 1) : 0;

    float acc[CO_T][2][4];
    #pragma unroll
    for (int u = 0; u < CO_T; ++u)
        #pragma unroll
        for (int p = 0; p < 2; ++p)
            acc[u][p][0] = acc[u][p][1] = acc[u][p][2] = acc[u][p][3] = 0.f;

    for (int ci0 = 0; ci0 < Cin; ci0 += CICHUNK) {
        if (ci0) __syncthreads();
        stage_weights<Cin, CO_T, CICHUNK>(wb, ci0, wlds);
        __syncthreads();

        for (int cic = 0; cic < CICHUNK; ++cic) {
            const int ci = ci0 + cic;
            const float* xp = xn + (size_t)ci * Hin * Win;
            float xr[3][4];
            {
                const int rows[3] = {ro0, i, ro2};
                const bool rvn[3] = {rm0, true, rm2};
                #pragma unroll
                for (int r = 0; r < 3; ++r) {
                    const float* rp = xp + (size_t)rows[r] * Win;
                    float2 m = *(const float2*)(rp + j0);
                    float eL = cmL ? rp[j0 - 1] : 0.f;
                    float eR = cmR ? rp[j0 + 2] : 0.f;
                    bool rk = rvn[r];
                    xr[r][0] = rk ? eL : 0.f;
                    xr[r][1] = rk ? m.x : 0.f;
                    xr[r][2] = rk ? m.y : 0.f;
                    xr[r][3] = rk ? eR : 0.f;
                }
            }
            #pragma unroll
            for (int u = 0; u < CO_T; ++u) {
                const int wbase = (cic * CO_T + u) * 4;
                float4 wq0 = wlds[wbase + 0];
                float4 wq1 = wlds[wbase + 1];
                float4 wq2 = wlds[wbase + 2];
                float4 wq3 = wlds[wbase + 3];
                #pragma unroll
                for (int p = 0; p < 2; ++p) {
                    float x00 = xr[0][p], x01 = xr[0][p + 1], x02 = xr[0][p + 2];
                    float x10 = xr[1][p], x11 = xr[1][p + 1], x12 = xr[1][p + 2];
                    float x20 = xr[2][p], x21 = xr[2][p + 1], x22 = xr[2][p + 2];
                    float* a = acc[u][p];
                    a[0] = fmaf(x00, wq0.x, a[0]); a[0] = fmaf(x01, wq0.z, a[0]);
                    a[0] = fmaf(x10, wq2.x, a[0]); a[0] = fmaf(x11, wq2.z, a[0]);
                    a[1] = fmaf(x01, wq0.y, a[1]); a[1] = fmaf(x02, wq0.w, a[1]);
                    a[1] = fmaf(x11, wq2.y, a[1]); a[1] = fmaf(x12, wq2.w, a[1]);
                    a[2] = fmaf(x10, wq1.x, a[2]); a[2] = fmaf(x11, wq1.z, a[2]);
                    a[2] = fmaf(x20, wq3.x, a[2]); a[2] = fmaf(x21, wq3.z, a[2]);
                    a[3] = fmaf(x11, wq1.y, a[3]); a[3] = fmaf(x12, wq1.w, a[3]);
                    a[3] = fmaf(x21, wq3.y, a[3]); a[3] = fmaf(x22, wq3.w, a[3]);
                }
            }
        }
    }

    constexpr int Hout = Hin * 2, Wout = Win * 2;
    #pragma unroll
    for (int u = 0; u < CO_T; ++u) {
        float b = bias[co0 + u];
        float r00 = acc[u][0][0] + b, r01 = acc[u][0][1] + b;
        float r02 = acc[u][1][0] + b, r03 = acc[u][1][1] + b;
        float r10 = acc[u][0][2] + b, r11 = acc[u][0][3] + b;
        float r12 = acc[u][1][2] + b, r13 = acc[u][1][3] + b;
        if (TANH) {
            r00 = tanhf(r00); r01 = tanhf(r01); r02 = tanhf(r02); r03 = tanhf(r03);
            r10 = tanhf(r10); r11 = tanhf(r11); r12 = tanhf(r12); r13 = tanhf(r13);
        }
        float* yp = y + (((size_t)(n * Cout + co0 + u)) * Hout + (i << 1)) * Wout + (jt << 2);
        float4 o;
        o.x = r00; o.y = r01; o.z = r02; o.w = r03; *(float4*)yp = o;
        o.x = r10; o.y = r11; o.z = r12; o.w = r13; *(float4*)(yp + Wout) = o;
    }
}

// ================================ launch ===================================
extern "C" void kernel_launch(void* const* d_in, const int* in_sizes, int n_in,
                              void* d_out, int out_size, void* d_ws, size_t ws_size,
                              hipStream_t stream)
{
    const float* x       = (const float*)d_in[0];
    const float* enc0_w  = (const float*)d_in[1];
    const float* enc0_b  = (const float*)d_in[2];
    const float* enc0_g  = (const float*)d_in[3];
    const float* enc0_bt = (const float*)d_in[4];
    const float* enc1_w  = (const float*)d_in[5];
    const float* enc1_b  = (const float*)d_in[6];
    const float* enc1_g  = (const float*)d_in[7];
    const float* enc1_bt = (const float*)d_in[8];
    const float* enc2_w  = (const float*)d_in[9];
    const float* enc2_b  = (const float*)d_in[10];
    const float* enc2_g  = (const float*)d_in[11];
    const float* enc2_bt = (const float*)d_in[12];
    const float* enc3_w  = (const float*)d_in[13];
    const float* enc3_b  = (const float*)d_in[14];
    const float* codebook= (const float*)d_in[15];
    const float* dec0_w  = (const float*)d_in[16];
    const float* dec0_b  = (const float*)d_in[17];
    const float* dec1_w  = (const float*)d_in[18];
    const float* dec1_b  = (const float*)d_in[19];
    const float* dec1_g  = (const float*)d_in[20];
    const float* dec1_bt = (const float*)d_in[21];
    const float* dec2_w  = (const float*)d_in[22];
    const float* dec2_b  = (const float*)d_in[23];
    const float* dec2_g  = (const float*)d_in[24];
    const float* dec2_bt = (const float*)d_in[25];
    const float* dec3_w  = (const float*)d_in[26];
    const float* dec3_b  = (const float*)d_in[27];

    float* ws = (float*)d_ws;
    float*  A  = ws;                       // 33,554,432 floats (134 MB)
    float*  B  = ws + 33554432;            // 16,777,216 floats (67 MB)
    float*  C  = ws + 50331648;            //  8,388,608 floats (33.6 MB)
    float*  Z  = ws + 58720256;            //    524,288 floats (2 MB)
    float*  CN = ws + 59244544;            //      1,024 floats
    float2* GP = (float2*)(ws + 59245568); //      8,192 float2 (gn partials)

    // split-weight scratch, time-multiplexed:
    ushort_t* WE1 = (ushort_t*)C;                 // enc1: 3*16*256*128 us (3.1 MB); C dead pre-enc2
    ushort_t* WE2 = (ushort_t*)A;                 // enc2: 3*16*512*256 us (12.6 MB); A dead post-enc1
    ushort_t* WD1 = (ushort_t*)C;                 // dec1: 4*256*512*4 us (4.2 MB); C dead post-enc3
    ushort_t* WD2 = (ushort_t*)(C + 4194304);     // dec2: 4*128*256*4 us (1 MB)

    float* out   = (float*)d_out;
    float* recon = out;                    // 3,145,728 floats
    float* qbuf  = out + 3145728;          //   524,288 floats
    float* idxf  = out + 3670016;          //    16,384 floats

    const dim3 blk(256);
    const int K = 16;
    const dim3 gngrid(K, 512);

    // ---------------- encoder ----------------
    wsplit_enc<256, 128><<<dim3(2048), blk, 0, stream>>>(enc1_w, WE1);

    conv4s2_k<3, 128, 256, 256, 8><<<dim3(16, 16, 16), blk, 0, stream>>>(
        x, enc0_w, enc0_b, A);
    gn_stats<<<gngrid, blk, 0, stream>>>(A, GP, 14, 4, K);
    gn_apply<<<gngrid, blk, 0, stream>>>(A, enc0_g, enc0_bt, GP, 14, 4, K);

    // enc1: 16x128x128x128 -> 16x256x64x64  (MFMA tap-GEMM, split-3)
    mfenc<128, 256, 128, 128><<<dim3(128, 1, 16), blk, 0, stream>>>(
        A, WE1, enc1_b, B);

    wsplit_enc<512, 256><<<dim3(8192), blk, 0, stream>>>(enc2_w, WE2);

    gn_stats<<<gngrid, blk, 0, stream>>>(B, GP, 12, 8, K);
    gn_apply<<<gngrid, blk, 0, stream>>>(B, enc1_g, enc1_bt, GP, 12, 8, K);

    // enc2: -> 16x512x32x32  (MFMA tap-GEMM, split-3)
    mfenc<256, 512, 64, 64><<<dim3(32, 2, 16), blk, 0, stream>>>(
        B, WE2, enc2_b, C);
    gn_stats<<<gngrid, blk, 0, stream>>>(C, GP, 10, 16, K);
    gn_apply<<<gngrid, blk, 0, stream>>>(C, enc2_g, enc2_bt, GP, 10, 16, K);

    conv1x1_k<512, 32, 1024, 8><<<dim3(4, 4, 16), blk, 0, stream>>>(
        C, enc3_w, enc3_b, Z);

    // ---------------- VQ ----------------
    cb_norm<<<dim3(4), blk, 0, stream>>>(codebook, CN);
    vq_kernel<<<dim3(16384 / 4), blk, 0, stream>>>(Z, codebook, CN, qbuf, idxf);

    // ---------------- decoder (round-7 path) ------------------------------
    wsplit_convt<256, 512, 1><<<dim3(8192), blk, 0, stream>>>(dec1_w, WD1);
    wsplit_convt<128, 256, 1><<<dim3(2048), blk, 0, stream>>>(dec2_w, WD2);

    conv1x1_k<32, 512, 1024, 8><<<dim3(4, 64, 16), blk, 0, stream>>>(
        qbuf, dec0_w, dec0_b, A);

    mfconvt<512, 256, 32, 32, 4, 1, 16, 1><<<dim3(128, 2, 16), blk, 0, stream>>>(
        A, WD1, dec1_b, B);
    gn_stats<<<gngrid, blk, 0, stream>>>(B, GP, 12, 8, K);
    gn_apply<<<gngrid, blk, 0, stream>>>(B, dec1_g, dec1_bt, GP, 12, 8, K);

    mfconvt<256, 128, 64, 64, 2, 2, 16, 1><<<dim3(256, 2, 16), blk, 0, stream>>>(
        B, WD2, dec2_b, A);
    gn_stats<<<gngrid, blk, 0, stream>>>(A, GP, 14, 4, K);
    gn_apply<<<gngrid, blk, 0, stream>>>(A, dec2_g, dec2_bt, GP, 14, 4, K);

    convt2_lds<128, 3, 128, 128, 3, 128, true><<<dim3(32, 1, 16), blk, 0, stream>>>(
        A, dec3_w, dec3_b, recon);
}

// Round 9
// 3321.197 us; speedup vs baseline: 1.8998x; 1.0309x over previous
//
#include <hip/hip_runtime.h>
#include <hip/hip_bf16.h>
#include <math.h>

// ---------------------------------------------------------------------------
// VQGAN forward, round 9.
//  - mfenc v2: same verified tap-GEMM geometry as round 8 (idx-exact), but
//    (a) dword-granular conflict-free LDS staging (ci-pair packing),
//    (b) tap loop unrolled x2 so weight loads pipeline.
//    Staged bits identical to round 8 -> z bit-identical -> idx exact.
//  - decoder: round-7/8 kernels unchanged.
// d_out = [recon 16*3*256*256 | q 16*32*32*32 | idx-as-float 16384]
// ---------------------------------------------------------------------------

#define EPS 1e-5f
typedef unsigned short ushort_t;
typedef unsigned int uint32;
typedef __attribute__((ext_vector_type(8))) short bf16x8;
typedef __attribute__((ext_vector_type(4))) float f32x4;
typedef __attribute__((ext_vector_type(4))) unsigned int u32x4;

__device__ __forceinline__ ushort_t f2bf(float x) {
    __hip_bfloat16 h = __float2bfloat16(x);
    return __builtin_bit_cast(ushort_t, h);
}
__device__ __forceinline__ float bf2f(ushort_t u) {
    __hip_bfloat16 h = __builtin_bit_cast(__hip_bfloat16, u);
    return __bfloat162float(h);
}
template <int NS>
__device__ __forceinline__ void splitNS(float x, ushort_t* p) {
    float r = x;
    #pragma unroll
    for (int s = 0; s < NS; ++s) {
        ushort_t u = f2bf(r);
        p[s] = u;
        if (s + 1 < NS) r -= bf2f(u);
    }
}

// ============ encoder weight pre-split: [s][tap][Cout][Cin] ================
template <int Cout, int Cin>
__global__ __launch_bounds__(256) void wsplit_enc(
    const float* __restrict__ w, ushort_t* __restrict__ o)
{
    int idx = blockIdx.x * 256 + threadIdx.x;
    if (idx >= Cout * Cin * 16) return;
    int tap = idx & 15;
    int ci  = (idx >> 4) % Cin;
    int co  = (idx >> 4) / Cin;
    ushort_t sp[3];
    splitNS<3>(w[idx], sp);
    #pragma unroll
    for (int s = 0; s < 3; ++s)
        o[((size_t)(s * 16 + tap) * Cout + co) * Cin + ci] = sp[s];
}

// ================= MFMA encoder conv k4 s2 p1: tap-GEMMs ===================
// Geometry identical to round 8 (verified): one oh, 32 m, 256 co, k=ci, KC=32.
// LDS: [s(3)][row(4)][ciq(4)][cpos(68)][cie(8)] ushort; col c -> cpos =
// (c>>1)+(c&1)*34. v2 staging: thread owns ci-pair (2*p16, 2*p16+1) and cols
// c = cg+16t -> packs one dword (lo=ci even, hi=ci odd) per s -> ds_write_b32
// with 2-way-max bank pattern (free). Fragment reads unchanged (b128).
template <int Cin, int Cout, int Hin, int Win>
__global__ __launch_bounds__(256) void mfenc(
    const float* __restrict__ x, const ushort_t* __restrict__ wsp,
    const float* __restrict__ bias, float* __restrict__ y)
{
    constexpr int Hout = Hin / 2, Wout = Win / 2;
    constexpr int MB = 32;
    constexpr int MT = Wout / MB;
    constexpr int NCOL = 66;
    constexpr int KC = 32;
    __shared__ ushort_t Xs[3 * 4 * 4 * 68 * 8];   // 52224 B
    uint32* __restrict__ Xs32 = (uint32*)Xs;

    const int n  = blockIdx.z;
    const int oh = blockIdx.x / MT;
    const int mt = blockIdx.x % MT;
    const int M0 = mt * MB;
    const int co_base = blockIdx.y * 256;
    const int tid = threadIdx.x;
    const int wv = tid >> 6, lane = tid & 63;
    const int q = lane >> 4, l15 = lane & 15;
    const int co_w0 = co_base + wv * 64;

    int ro[4]; bool rv[4];
    #pragma unroll
    for (int k = 0; k < 4; ++k) {
        int r = 2 * oh - 1 + k;
        rv[k] = (r >= 0) && (r < Hin);
        ro[k] = rv[k] ? r : 0;
    }

    f32x4 acc[4][2];
    #pragma unroll
    for (int a = 0; a < 4; ++a)
        #pragma unroll
        for (int b = 0; b < 2; ++b) acc[a][b] = (f32x4){0.f, 0.f, 0.f, 0.f};

    // v2 staging ids: ci-pair + column-group
    const int p16  = tid >> 4;            // 0..15 -> ci pair (2*p16, 2*p16+1)
    const int cg   = tid & 15;            // column group
    const int sciq = p16 >> 2;            // ci octet 0..3
    const int cieP = p16 & 3;             // dword index within octet

    for (int ci0 = 0; ci0 < Cin; ci0 += KC) {
        if (ci0) __syncthreads();
        {
            const float* pl0 = x + (size_t)(n * Cin + ci0 + 2 * p16) * Hin * Win;
            const float* pl1 = pl0 + (size_t)Hin * Win;
            #pragma unroll
            for (int r = 0; r < 4; ++r) {
                const float* rp0 = pl0 + (size_t)ro[r] * Win;
                const float* rp1 = pl1 + (size_t)ro[r] * Win;
                const bool rok = rv[r];
                for (int c = cg; c < NCOL; c += 16) {
                    const int gc = 2 * M0 - 1 + c;
                    const bool ok = rok && (gc >= 0) && (gc < Win);
                    float v0 = ok ? rp0[gc] : 0.f;
                    float v1 = ok ? rp1[gc] : 0.f;
                    ushort_t s0[3], s1[3];
                    splitNS<3>(v0, s0);
                    splitNS<3>(v1, s1);
                    const int cpos = (c >> 1) + (c & 1) * 34;
                    #pragma unroll
                    for (int s = 0; s < 3; ++s)
                        Xs32[((((s * 4 + r) * 4 + sciq) * 68) + cpos) * 4 + cieP] =
                            (uint32)s0[s] | ((uint32)s1[s] << 16);
                }
            }
        }
        __syncthreads();

        #pragma unroll 2
        for (int tap = 0; tap < 16; ++tap) {
            const int kh = tap >> 2, kw = tap & 3;
            bf16x8 af[4][3];
            #pragma unroll
            for (int cf = 0; cf < 4; ++cf) {
                const int co = co_w0 + cf * 16 + l15;
                #pragma unroll
                for (int s = 0; s < 3; ++s)
                    af[cf][s] = *(const bf16x8*)(wsp +
                        ((size_t)(s * 16 + tap) * Cout + co) * Cin + ci0 + q * 8);
            }
            bf16x8 bx[2][3];
            const int cpbase = (kw >> 1) + (kw & 1) * 34;
            #pragma unroll
            for (int mf = 0; mf < 2; ++mf) {
                const int cpos = (mf * 16 + l15) + cpbase;
                #pragma unroll
                for (int s = 0; s < 3; ++s)
                    bx[mf][s] = *(const bf16x8*)(&Xs[((((s * 4 + kh) * 4 + q) * 68) + cpos) * 8]);
            }
            #pragma unroll
            for (int sa = 0; sa < 3; ++sa)
                #pragma unroll
                for (int sb = 0; sb < 3; ++sb) {
                    if (sa + sb >= 3) continue;
                    #pragma unroll
                    for (int cf = 0; cf < 4; ++cf)
                        #pragma unroll
                        for (int mf = 0; mf < 2; ++mf)
                            acc[cf][mf] = __builtin_amdgcn_mfma_f32_16x16x32_bf16(
                                af[cf][sa], bx[mf][sb], acc[cf][mf], 0, 0, 0);
                }
        }
    }

    #pragma unroll
    for (int cf = 0; cf < 4; ++cf)
        #pragma unroll
        for (int mf = 0; mf < 2; ++mf) {
            const int ow = M0 + mf * 16 + l15;
            #pragma unroll
            for (int rg = 0; rg < 4; ++rg) {
                const int co = co_w0 + cf * 16 + q * 4 + rg;
                y[(((size_t)n * Cout + co) * Hout + oh) * Wout + ow] =
                    acc[cf][mf][rg] + bias[co];
            }
        }
}

// ============== decoder weight pre-split (round-7, NS=1) ===================
template <int Cout, int Cin, int NS>
__global__ __launch_bounds__(256) void wsplit_convt(
    const float* __restrict__ w, ushort_t* __restrict__ o)
{
    int idx = blockIdx.x * 256 + threadIdx.x;
    if (idx >= 4 * Cout * Cin * 4) return;
    int b  = idx & 1;
    int a  = (idx >> 1) & 1;
    int ci = (idx >> 2) % Cin;
    int co = ((idx >> 2) / Cin) % Cout;
    int p  = ((idx >> 2) / Cin) / Cout;
    int di = p >> 1, dj = p & 1;
    float v = w[(((size_t)co * Cin + ci) * 4 + (2 * a + di)) * 4 + (2 * b + dj)];
    ushort_t sp[NS];
    splitNS<NS>(v, sp);
    #pragma unroll
    for (int s = 0; s < NS; ++s)
        o[(((size_t)(s * 4 + p) * Cout + co) * Cin + ci) * 4 + a * 2 + b] = sp[s];
}

// ================= MFMA convT (round-7, unchanged) =========================
template <int Cin, int Cout, int Hin, int Win, int CO_WAVES, int M_WAVES, int KC, int NS>
__global__ __launch_bounds__(256) void mfconvt(
    const float* __restrict__ x, const ushort_t* __restrict__ wsp,
    const float* __restrict__ bias, float* __restrict__ y)
{
    constexpr int NDp = Win / 2 + 2;
    constexpr int CO_B = CO_WAVES * 32;
    static_assert(CO_WAVES * M_WAVES == 4, "4 waves");
    static_assert(M_WAVES * 32 == Win, "block spans full row");
    static_assert(KC % 8 == 0, "k-step = 8 ci");
    __shared__ unsigned int Xs[NS * KC * 2 * 2 * NDp];

    const int bi = blockIdx.x;
    const int i = bi >> 2;
    const int p = bi & 3;
    const int di = p >> 1, dj = p & 1;
    const int n = blockIdx.z;
    const int co_base = blockIdx.y * CO_B;
    const int tid = threadIdx.x;
    const int wv = tid >> 6, lane = tid & 63;
    const int cw = wv / M_WAVES, mw = wv % M_WAVES;
    const int co_w0 = co_base + cw * 32;
    const int m_w0 = mw * 32;
    const int q = lane >> 4, l15 = lane & 15;

    const int r0 = i - 1 + di, r1 = i + di;
    const bool v0 = (r0 >= 0), v1 = (r1 < Hin);
    const int r0c = v0 ? r0 : 0, r1c = v1 ? r1 : 0;

    f32x4 acc[2][2];
    #pragma unroll
    for (int a = 0; a < 2; ++a)
        #pragma unroll
        for (int b = 0; b < 2; ++b) acc[a][b] = (f32x4){0.f, 0.f, 0.f, 0.f};

    constexpr int SEGW = Win / 4;
    constexpr int SEGS = KC * 2 * SEGW;

    for (int ci0 = 0; ci0 < Cin; ci0 += KC) {
        if (ci0) __syncthreads();
        for (int seg = tid; seg < SEGS; seg += 256) {
            const int c0 = (seg % SEGW) * 4;
            const int rem = seg / SEGW;
            const int a = rem & 1;
            const int ci = rem >> 1;
            const bool rok = a ? v1 : v0;
            const int gr = a ? r1c : r0c;
            const float* rp = x + ((size_t)(n * Cin + ci0 + ci) * Hin + gr) * Win;
            float v[5];
            v[0] = (rok && c0 > 0) ? rp[c0 - 1] : 0.f;
            #pragma unroll
            for (int t = 1; t < 5; ++t) v[t] = rok ? rp[c0 + t - 1] : 0.f;
            ushort_t sp[5][NS];
            #pragma unroll
            for (int t = 0; t < 5; ++t) splitNS<NS>(v[t], sp[t]);
            #pragma unroll
            for (int s = 0; s < NS; ++s) {
                const int base = ((s * KC + ci) * 2 + a) * 2 * NDp;
                Xs[base + (c0 >> 1)]           = (unsigned)sp[1][s] | ((unsigned)sp[2][s] << 16);
                Xs[base + (c0 >> 1) + 1]       = (unsigned)sp[3][s] | ((unsigned)sp[4][s] << 16);
                Xs[base + NDp + (c0 >> 1)]     = (unsigned)sp[0][s] | ((unsigned)sp[1][s] << 16);
                Xs[base + NDp + (c0 >> 1) + 1] = (unsigned)sp[2][s] | ((unsigned)sp[3][s] << 16);
                if (c0 == Win - 4)
                    Xs[base + NDp + (Win >> 1)] = (unsigned)sp[4][s];
            }
        }
        __syncthreads();

        #pragma unroll
        for (int cs = 0; cs < KC; cs += 8) {
            bf16x8 af[2][NS];
            #pragma unroll
            for (int cf = 0; cf < 2; ++cf) {
                const int co = co_w0 + cf * 16 + l15;
                #pragma unroll
                for (int s = 0; s < NS; ++s) {
                    const ushort_t* ap = wsp +
                        ((size_t)(s * 4 + p) * Cout + co) * ((size_t)Cin * 4) +
                        (size_t)(ci0 + cs) * 4 + q * 8;
                    af[cf][s] = *(const bf16x8*)ap;
                }
            }
            bf16x8 bfr[2][NS];
            const int ciA = cs + q * 2;
            #pragma unroll
            for (int mf = 0; mf < 2; ++mf) {
                const int m = m_w0 + mf * 16 + l15;
                const int c = m - 1 + dj;
                const int copy = c & 1;
                const int idx = (c + 1) >> 1;
                #pragma unroll
                for (int s = 0; s < NS; ++s) {
                    u32x4 bd;
                    bd.x = Xs[((s * KC + ciA) * 2 + 0) * 2 * NDp + copy * NDp + idx];
                    bd.y = Xs[((s * KC + ciA) * 2 + 1) * 2 * NDp + copy * NDp + idx];
                    bd.z = Xs[((s * KC + ciA + 1) * 2 + 0) * 2 * NDp + copy * NDp + idx];
                    bd.w = Xs[((s * KC + ciA + 1) * 2 + 1) * 2 * NDp + copy * NDp + idx];
                    bfr[mf][s] = __builtin_bit_cast(bf16x8, bd);
                }
            }
            #pragma unroll
            for (int sa = 0; sa < NS; ++sa)
                #pragma unroll
                for (int sb = 0; sb < NS; ++sb) {
                    if (sa + sb >= NS) continue;
                    #pragma unroll
                    for (int cf = 0; cf < 2; ++cf)
                        #pragma unroll
                        for (int mf = 0; mf < 2; ++mf)
                            acc[cf][mf] = __builtin_amdgcn_mfma_f32_16x16x32_bf16(
                                af[cf][sa], bfr[mf][sb], acc[cf][mf], 0, 0, 0);
                }
        }
    }

    constexpr int Ho2 = Hin * 2, Wo2 = Win * 2;
    const int orow = 2 * i + di;
    #pragma unroll
    for (int cf = 0; cf < 2; ++cf)
        #pragma unroll
        for (int mf = 0; mf < 2; ++mf) {
            const int ocol = 2 * (m_w0 + mf * 16 + l15) + dj;
            #pragma unroll
            for (int rg = 0; rg < 4; ++rg) {
                const int co = co_w0 + cf * 16 + q * 4 + rg;
                y[(((size_t)n * Cout + co) * Ho2 + orow) * Wo2 + ocol] =
                    acc[cf][mf][rg] + bias[co];
            }
        }
}

// ============== conv k4 s2 p1 (round-3 proven fp32) — enc0 only ============
template <int Cin, int Cout, int Hin, int Win, int CO_T>
__global__ __launch_bounds__(256) void conv4s2_k(
    const float* __restrict__ x, const float* __restrict__ w,
    const float* __restrict__ bias, float* __restrict__ y)
{
    constexpr int Hout = Hin / 2, Wout = Win / 2, Wt = Wout / 4;
    const int n   = blockIdx.z;
    const int co0 = blockIdx.y * CO_T;
    const int local = blockIdx.x * 256 + threadIdx.x;
    const int wt = local & (Wt - 1);
    const int oh = local / Wt;
    const int iw0 = (wt << 3) - 1;
    const int ih0 = (oh << 1) - 1;

    const float* __restrict__ xn = x + (size_t)n * Cin * Hin * Win;
    const float* __restrict__ wb = w + (size_t)co0 * Cin * 16;

    const bool cL = (wt > 0);
    const bool cR = (wt < Wt - 1);

    float acc[CO_T][4];
    #pragma unroll
    for (int u = 0; u < CO_T; ++u)
        acc[u][0] = acc[u][1] = acc[u][2] = acc[u][3] = 0.f;

    bool rv[4]; int ro[4];
    #pragma unroll
    for (int k = 0; k < 4; ++k) {
        int r = ih0 + k;
        rv[k] = (r >= 0) && (r < Hin);
        ro[k] = rv[k] ? r : 0;
    }

    for (int ci = 0; ci < Cin; ++ci) {
        const float* xp = xn + (size_t)ci * Hin * Win;
        float xv[4][10];
        #pragma unroll
        for (int k = 0; k < 4; ++k) {
            const float* rp = xp + (size_t)ro[k] * Win;
            float4 m0 = *(const float4*)(rp + (wt << 3));
            float4 m1 = *(const float4*)(rp + (wt << 3) + 4);
            float e0 = cL ? rp[iw0] : 0.f;
            float e9 = cR ? rp[iw0 + 9] : 0.f;
            bool rk = rv[k];
            xv[k][0] = rk ? e0 : 0.f;
            xv[k][1] = rk ? m0.x : 0.f;
            xv[k][2] = rk ? m0.y : 0.f;
            xv[k][3] = rk ? m0.z : 0.f;
            xv[k][4] = rk ? m0.w : 0.f;
            xv[k][5] = rk ? m1.x : 0.f;
            xv[k][6] = rk ? m1.y : 0.f;
            xv[k][7] = rk ? m1.z : 0.f;
            xv[k][8] = rk ? m1.w : 0.f;
            xv[k][9] = rk ? e9 : 0.f;
        }
        #pragma unroll
        for (int u = 0; u < CO_T; ++u) {
            const float* wp = wb + ((size_t)u * Cin + ci) * 16;
            #pragma unroll
            for (int kh = 0; kh < 4; ++kh) {
                #pragma unroll
                for (int kw = 0; kw < 4; ++kw) {
                    float wv = wp[kh * 4 + kw];
                    acc[u][0] = fmaf(xv[kh][kw + 0], wv, acc[u][0]);
                    acc[u][1] = fmaf(xv[kh][kw + 2], wv, acc[u][1]);
                    acc[u][2] = fmaf(xv[kh][kw + 4], wv, acc[u][2]);
                    acc[u][3] = fmaf(xv[kh][kw + 6], wv, acc[u][3]);
                }
            }
        }
    }

    #pragma unroll
    for (int u = 0; u < CO_T; ++u) {
        float b = bias[co0 + u];
        float4 o;
        o.x = acc[u][0] + b; o.y = acc[u][1] + b;
        o.z = acc[u][2] + b; o.w = acc[u][3] + b;
        float* yp = y + (((size_t)(n * Cout + co0 + u)) * Hout + oh) * Wout + (wt << 2);
        *(float4*)yp = o;
    }
}

// ==================== GroupNorm 2-stage (proven) ===========================
__global__ __launch_bounds__(256) void gn_stats(
    const float* __restrict__ y, float2* __restrict__ part,
    int HWshift, int grpC, int K)
{
    const int kblk = blockIdx.x;
    const int bg = blockIdx.y;
    const int b = bg >> 5, g = bg & 31;
    const int C = grpC << 5;
    const size_t base = ((size_t)b * C + (size_t)g * grpC) << HWshift;
    const int count4 = (grpC << HWshift) >> 2;
    const int chunk4 = count4 / K;
    const int ofs4 = kblk * chunk4;
    const float4* y4 = (const float4*)(y + base);

    float s = 0.f, ss = 0.f;
    for (int i = ofs4 + threadIdx.x; i < ofs4 + chunk4; i += 256) {
        float4 v = y4[i];
        s += v.x + v.y + v.z + v.w;
        ss = fmaf(v.x, v.x, ss); ss = fmaf(v.y, v.y, ss);
        ss = fmaf(v.z, v.z, ss); ss = fmaf(v.w, v.w, ss);
    }
    __shared__ float sh0[256];
    __shared__ float sh1[256];
    sh0[threadIdx.x] = s; sh1[threadIdx.x] = ss;
    __syncthreads();
    for (int off = 128; off > 0; off >>= 1) {
        if (threadIdx.x < off) {
            sh0[threadIdx.x] += sh0[threadIdx.x + off];
            sh1[threadIdx.x] += sh1[threadIdx.x + off];
        }
        __syncthreads();
    }
    if (threadIdx.x == 0) {
        float2 pp; pp.x = sh0[0]; pp.y = sh1[0];
        part[bg * K + kblk] = pp;
    }
}

__global__ __launch_bounds__(256) void gn_apply(
    float* __restrict__ y, const float* __restrict__ gamma,
    const float* __restrict__ beta, const float2* __restrict__ part,
    int HWshift, int grpC, int K)
{
    const int kblk = blockIdx.x;
    const int bg = blockIdx.y;
    const int b = bg >> 5, g = bg & 31;
    const int C = grpC << 5;
    const size_t base = ((size_t)b * C + (size_t)g * grpC) << HWshift;
    const int count4 = (grpC << HWshift) >> 2;
    const int chunk4 = count4 / K;
    const int ofs4 = kblk * chunk4;
    float4* y4 = (float4*)(y + base);

    float s = 0.f, ss = 0.f;
    for (int k = 0; k < K; ++k) {
        float2 pp = part[bg * K + k];
        s += pp.x; ss += pp.y;
    }
    const float inv = 1.f / (float)(count4 * 4);
    const float mean = s * inv;
    const float var = ss * inv - mean * mean;
    const float rstd = rsqrtf(var + EPS);

    const int HW4shift = HWshift - 2;
    for (int i = ofs4 + threadIdx.x; i < ofs4 + chunk4; i += 256) {
        int c = g * grpC + (i >> HW4shift);
        float ga = gamma[c], be = beta[c];
        float4 v = y4[i];
        float t0 = (v.x - mean) * rstd * ga + be;
        float t1 = (v.y - mean) * rstd * ga + be;
        float t2 = (v.z - mean) * rstd * ga + be;
        float t3 = (v.w - mean) * rstd * ga + be;
        v.x = t0 / (1.f + __expf(-t0));
        v.y = t1 / (1.f + __expf(-t1));
        v.z = t2 / (1.f + __expf(-t2));
        v.w = t3 / (1.f + __expf(-t3));
        y4[i] = v;
    }
}

// ====================== 1x1 conv (proven) ==================================
template <int Cin, int Cout, int HW, int CO_T>
__global__ __launch_bounds__(256) void conv1x1_k(
    const float* __restrict__ x, const float* __restrict__ w,
    const float* __restrict__ bias, float* __restrict__ y)
{
    const int n = blockIdx.z;
    const int co0 = blockIdx.y * CO_T;
    const int s = blockIdx.x * 256 + threadIdx.x;
    const float* xp = x + (size_t)n * Cin * HW + s;

    float acc[CO_T];
    #pragma unroll
    for (int u = 0; u < CO_T; ++u) acc[u] = bias[co0 + u];

    for (int ci = 0; ci < Cin; ++ci) {
        float v = xp[(size_t)ci * HW];
        #pragma unroll
        for (int u = 0; u < CO_T; ++u)
            acc[u] = fmaf(v, w[(size_t)(co0 + u) * Cin + ci], acc[u]);
    }
    #pragma unroll
    for (int u = 0; u < CO_T; ++u)
        y[(size_t)(n * Cout + co0 + u) * HW + s] = acc[u];
}

// ============================== VQ (proven) ================================
__global__ __launch_bounds__(256) void cb_norm(
    const float* __restrict__ cb, float* __restrict__ cn)
{
    int j = blockIdx.x * 256 + threadIdx.x;
    const float* c = cb + (size_t)j * 32;
    float s = 0.f;
    #pragma unroll
    for (int k = 0; k < 32; ++k) s = fmaf(c[k], c[k], s);
    cn[j] = s;
}

__global__ __launch_bounds__(256) void vq_kernel(
    const float* __restrict__ z, const float* __restrict__ cb,
    const float* __restrict__ cn, float* __restrict__ q,
    float* __restrict__ idxf)
{
    const int row = blockIdx.x * 4 + (threadIdx.x >> 6);
    const int lane = threadIdx.x & 63;
    const float* zr = z + (size_t)row * 32;
    float zreg[32];
    #pragma unroll
    for (int k = 0; k < 32; ++k) zreg[k] = zr[k];
    float zn = 0.f;
    #pragma unroll
    for (int k = 0; k < 32; ++k) zn = fmaf(zreg[k], zreg[k], zn);

    float best = 3.4e38f;
    int bj = 0;
    for (int ii = 0; ii < 16; ++ii) {
        int j = lane * 16 + ii;
        const float* c = cb + (size_t)j * 32;
        float dot = 0.f;
        #pragma unroll
        for (int k = 0; k < 32; ++k) dot = fmaf(zreg[k], c[k], dot);
        float d = zn + cn[j] - 2.f * dot;
        if (d < best) { best = d; bj = j; }
    }
    #pragma unroll
    for (int off = 1; off < 64; off <<= 1) {
        float ob = __shfl_xor(best, off);
        int oj = __shfl_xor(bj, off);
        if (ob < best || (ob == best && oj < bj)) { best = ob; bj = oj; }
    }
    if (lane < 32) q[(size_t)row * 32 + lane] = cb[(size_t)bj * 32 + lane];
    if (lane == 0) idxf[row] = (float)bj;
}

// ======= fp32 convT (round-4 proven) — dec3 (Cout=3, tanh) =================
template <int Cin, int CO_T, int CICHUNK>
__device__ __forceinline__ void stage_weights(
    const float* __restrict__ wb, int ci0, float4* __restrict__ lds4)
{
    constexpr int W4 = CICHUNK * CO_T * 4;
    for (int g4 = threadIdx.x; g4 < W4; g4 += blockDim.x) {
        int u = g4 / (CICHUNK * 4);
        int r4 = g4 - u * (CICHUNK * 4);
        lds4[g4] = ((const float4*)(wb + (size_t)u * Cin * 16 + (size_t)ci0 * 16))[r4];
    }
}

template <int Cin, int Cout, int Hin, int Win, int CO_T, int CICHUNK, bool TANH>
__global__ __launch_bounds__(256) void convt2_lds(
    const float* __restrict__ x, const float* __restrict__ w,
    const float* __restrict__ bias, float* __restrict__ y)
{
    constexpr int Wt2 = Win / 2;
    __shared__ float4 wlds[CICHUNK * CO_T * 4];

    const int n = blockIdx.z;
    const int co0 = blockIdx.y * CO_T;
    const int local = blockIdx.x * 256 + threadIdx.x;
    const int jt = local & (Wt2 - 1);
    const int i = local / Wt2;
    const int j0 = jt << 1;

    const float* __restrict__ xn = x + (size_t)n * Cin * Hin * Win;
    const float* __restrict__ wb = w + (size_t)co0 * Cin * 16;

    const bool rm0 = (i > 0), rm2 = (i + 1 < Hin);
    const bool cmL = (jt > 0), cmR = (jt < Wt2 - 1);
    const int ro0 = rm0 ? (i - 1) : 0;
    const int ro2 = rm2 ? (i + 1) : 0;

    float acc[CO_T][2][4];
    #pragma unroll
    for (int u = 0; u < CO_T; ++u)
        #pragma unroll
        for (int p = 0; p < 2; ++p)
            acc[u][p][0] = acc[u][p][1] = acc[u][p][2] = acc[u][p][3] = 0.f;

    for (int ci0 = 0; ci0 < Cin; ci0 += CICHUNK) {
        if (ci0) __syncthreads();
        stage_weights<Cin, CO_T, CICHUNK>(wb, ci0, wlds);
        __syncthreads();

        for (int cic = 0; cic < CICHUNK; ++cic) {
            const int ci = ci0 + cic;
            const float* xp = xn + (size_t)ci * Hin * Win;
            float xr[3][4];
            {
                const int rows[3] = {ro0, i, ro2};
                const bool rvn[3] = {rm0, true, rm2};
                #pragma unroll
                for (int r = 0; r < 3; ++r) {
                    const float* rp = xp + (size_t)rows[r] * Win;
                    float2 m = *(const float2*)(rp + j0);
                    float eL = cmL ? rp[j0 - 1] : 0.f;
                    float eR = cmR ? rp[j0 + 2] : 0.f;
                    bool rk = rvn[r];
                    xr[r][0] = rk ? eL : 0.f;
                    xr[r][1] = rk ? m.x : 0.f;
                    xr[r][2] = rk ? m.y : 0.f;
                    xr[r][3] = rk ? eR : 0.f;
                }
            }
            #pragma unroll
            for (int u = 0; u < CO_T; ++u) {
                const int wbase = (cic * CO_T + u) * 4;
                float4 wq0 = wlds[wbase + 0];
                float4 wq1 = wlds[wbase + 1];
                float4 wq2 = wlds[wbase + 2];
                float4 wq3 = wlds[wbase + 3];
                #pragma unroll
                for (int p = 0; p < 2; ++p) {
                    float x00 = xr[0][p], x01 = xr[0][p + 1], x02 = xr[0][p + 2];
                    float x10 = xr[1][p], x11 = xr[1][p + 1], x12 = xr[1][p + 2];
                    float x20 = xr[2][p], x21 = xr[2][p + 1], x22 = xr[2][p + 2];
                    float* a = acc[u][p];
                    a[0] = fmaf(x00, wq0.x, a[0]); a[0] = fmaf(x01, wq0.z, a[0]);
                    a[0] = fmaf(x10, wq2.x, a[0]); a[0] = fmaf(x11, wq2.z, a[0]);
                    a[1] = fmaf(x01, wq0.y, a[1]); a[1] = fmaf(x02, wq0.w, a[1]);
                    a[1] = fmaf(x11, wq2.y, a[1]); a[1] = fmaf(x12, wq2.w, a[1]);
                    a[2] = fmaf(x10, wq1.x, a[2]); a[2] = fmaf(x11, wq1.z, a[2]);
                    a[2] = fmaf(x20, wq3.x, a[2]); a[2] = fmaf(x21, wq3.z, a[2]);
                    a[3] = fmaf(x11, wq1.y, a[3]); a[3] = fmaf(x12, wq1.w, a[3]);
                    a[3] = fmaf(x21, wq3.y, a[3]); a[3] = fmaf(x22, wq3.w, a[3]);
                }
            }
        }
    }

    constexpr int Hout = Hin * 2, Wout = Win * 2;
    #pragma unroll
    for (int u = 0; u < CO_T; ++u) {
        float b = bias[co0 + u];
        float r00 = acc[u][0][0] + b, r01 = acc[u][0][1] + b;
        float r02 = acc[u][1][0] + b, r03 = acc[u][1][1] + b;
        float r10 = acc[u][0][2] + b, r11 = acc[u][0][3] + b;
        float r12 = acc[u][1][2] + b, r13 = acc[u][1][3] + b;
        if (TANH) {
            r00 = tanhf(r00); r01 = tanhf(r01); r02 = tanhf(r02); r03 = tanhf(r03);
            r10 = tanhf(r10); r11 = tanhf(r11); r12 = tanhf(r12); r13 = tanhf(r13);
        }
        float* yp = y + (((size_t)(n * Cout + co0 + u)) * Hout + (i << 1)) * Wout + (jt << 2);
        float4 o;
        o.x = r00; o.y = r01; o.z = r02; o.w = r03; *(float4*)yp = o;
        o.x = r10; o.y = r11; o.z = r12; o.w = r13; *(float4*)(yp + Wout) = o;
    }
}

// ================================ launch ===================================
extern "C" void kernel_launch(void* const* d_in, const int* in_sizes, int n_in,
                              void* d_out, int out_size, void* d_ws, size_t ws_size,
                              hipStream_t stream)
{
    const float* x       = (const float*)d_in[0];
    const float* enc0_w  = (const float*)d_in[1];
    const float* enc0_b  = (const float*)d_in[2];
    const float* enc0_g  = (const float*)d_in[3];
    const float* enc0_bt = (const float*)d_in[4];
    const float* enc1_w  = (const float*)d_in[5];
    const float* enc1_b  = (const float*)d_in[6];
    const float* enc1_g  = (const float*)d_in[7];
    const float* enc1_bt = (const float*)d_in[8];
    const float* enc2_w  = (const float*)d_in[9];
    const float* enc2_b  = (const float*)d_in[10];
    const float* enc2_g  = (const float*)d_in[11];
    const float* enc2_bt = (const float*)d_in[12];
    const float* enc3_w  = (const float*)d_in[13];
    const float* enc3_b  = (const float*)d_in[14];
    const float* codebook= (const float*)d_in[15];
    const float* dec0_w  = (const float*)d_in[16];
    const float* dec0_b  = (const float*)d_in[17];
    const float* dec1_w  = (const float*)d_in[18];
    const float* dec1_b  = (const float*)d_in[19];
    const float* dec1_g  = (const float*)d_in[20];
    const float* dec1_bt = (const float*)d_in[21];
    const float* dec2_w  = (const float*)d_in[22];
    const float* dec2_b  = (const float*)d_in[23];
    const float* dec2_g  = (const float*)d_in[24];
    const float* dec2_bt = (const float*)d_in[25];
    const float* dec3_w  = (const float*)d_in[26];
    const float* dec3_b  = (const float*)d_in[27];

    float* ws = (float*)d_ws;
    float*  A  = ws;                       // 33,554,432 floats (134 MB)
    float*  B  = ws + 33554432;            // 16,777,216 floats (67 MB)
    float*  C  = ws + 50331648;            //  8,388,608 floats (33.6 MB)
    float*  Z  = ws + 58720256;            //    524,288 floats (2 MB)
    float*  CN = ws + 59244544;            //      1,024 floats
    float2* GP = (float2*)(ws + 59245568); //      8,192 float2 (gn partials)

    // split-weight scratch, time-multiplexed:
    ushort_t* WE1 = (ushort_t*)C;                 // enc1 (3.1 MB); C dead pre-enc2
    ushort_t* WE2 = (ushort_t*)A;                 // enc2 (12.6 MB); A dead post-enc1
    ushort_t* WD1 = (ushort_t*)C;                 // dec1 (4.2 MB); C dead post-enc3
    ushort_t* WD2 = (ushort_t*)(C + 4194304);     // dec2 (1 MB)

    float* out   = (float*)d_out;
    float* recon = out;                    // 3,145,728 floats
    float* qbuf  = out + 3145728;          //   524,288 floats
    float* idxf  = out + 3670016;          //    16,384 floats

    const dim3 blk(256);
    const int K = 16;
    const dim3 gngrid(K, 512);

    // ---------------- encoder ----------------
    wsplit_enc<256, 128><<<dim3(2048), blk, 0, stream>>>(enc1_w, WE1);

    conv4s2_k<3, 128, 256, 256, 8><<<dim3(16, 16, 16), blk, 0, stream>>>(
        x, enc0_w, enc0_b, A);
    gn_stats<<<gngrid, blk, 0, stream>>>(A, GP, 14, 4, K);
    gn_apply<<<gngrid, blk, 0, stream>>>(A, enc0_g, enc0_bt, GP, 14, 4, K);

    // enc1: 16x128x128x128 -> 16x256x64x64  (MFMA tap-GEMM, split-3)
    mfenc<128, 256, 128, 128><<<dim3(128, 1, 16), blk, 0, stream>>>(
        A, WE1, enc1_b, B);

    wsplit_enc<512, 256><<<dim3(8192), blk, 0, stream>>>(enc2_w, WE2);

    gn_stats<<<gngrid, blk, 0, stream>>>(B, GP, 12, 8, K);
    gn_apply<<<gngrid, blk, 0, stream>>>(B, enc1_g, enc1_bt, GP, 12, 8, K);

    // enc2: -> 16x512x32x32  (MFMA tap-GEMM, split-3)
    mfenc<256, 512, 64, 64><<<dim3(32, 2, 16), blk, 0, stream>>>(
        B, WE2, enc2_b, C);
    gn_stats<<<gngrid, blk, 0, stream>>>(C, GP, 10, 16, K);
    gn_apply<<<gngrid, blk, 0, stream>>>(C, enc2_g, enc2_bt, GP, 10, 16, K);

    conv1x1_k<512, 32, 1024, 8><<<dim3(4, 4, 16), blk, 0, stream>>>(
        C, enc3_w, enc3_b, Z);

    // ---------------- VQ ----------------
    cb_norm<<<dim3(4), blk, 0, stream>>>(codebook, CN);
    vq_kernel<<<dim3(16384 / 4), blk, 0, stream>>>(Z, codebook, CN, qbuf, idxf);

    // ---------------- decoder (round-7 path) ------------------------------
    wsplit_convt<256, 512, 1><<<dim3(8192), blk, 0, stream>>>(dec1_w, WD1);
    wsplit_convt<128, 256, 1><<<dim3(2048), blk, 0, stream>>>(dec2_w, WD2);

    conv1x1_k<32, 512, 1024, 8><<<dim3(4, 64, 16), blk, 0, stream>>>(
        qbuf, dec0_w, dec0_b, A);

    mfconvt<512, 256, 32, 32, 4, 1, 16, 1><<<dim3(128, 2, 16), blk, 0, stream>>>(
        A, WD1, dec1_b, B);
    gn_stats<<<gngrid, blk, 0, stream>>>(B, GP, 12, 8, K);
    gn_apply<<<gngrid, blk, 0, stream>>>(B, dec1_g, dec1_bt, GP, 12, 8, K);

    mfconvt<256, 128, 64, 64, 2, 2, 16, 1><<<dim3(256, 2, 16), blk, 0, stream>>>(
        B, WD2, dec2_b, A);
    gn_stats<<<gngrid, blk, 0, stream>>>(A, GP, 14, 4, K);
    gn_apply<<<gngrid, blk, 0, stream>>>(A, dec2_g, dec2_bt, GP, 14, 4, K);

    convt2_lds<128, 3, 128, 128, 3, 128, true><<<dim3(32, 1, 16), blk, 0, stream>>>(
        A, dec3_w, dec3_b, recon);
}